// Round 4
// baseline (862.974 us; speedup 1.0000x reference)
//
#include <hip/hip_runtime.h>

typedef unsigned short u16;
typedef unsigned int u32;
typedef float f32x4 __attribute__((ext_vector_type(4)));
typedef __bf16 bf16x8 __attribute__((ext_vector_type(8)));

__device__ __forceinline__ u16 f2b(float f) {
    u32 b = __builtin_bit_cast(u32, f);
    b = b + 0x7FFFu + ((b >> 16) & 1u);
    return (u16)(b >> 16);
}

// ---------------- fp32 -> bf16 convert (4 elems/thread) ----------------
__global__ __launch_bounds__(256) void k_convert(const float* __restrict__ in,
                                                 u16* __restrict__ out, int n4) {
    int i = blockIdx.x * 256 + threadIdx.x;
    if (i >= n4) return;
    f32x4 v = reinterpret_cast<const f32x4*>(in)[i];
    ushort4 o;
    o.x = f2b(v.x); o.y = f2b(v.y); o.z = f2b(v.z); o.w = f2b(v.w);
    reinterpret_cast<ushort4*>(out)[i] = o;
}

// ---------------- generic NT bf16 GEMM, 2-phase prefetch (double-buffered global_load_lds) ----
// C[m,n] = scale * sum_k A[m,k]*B[n,k]  (+bias)(+relu)(+res), A,B bf16(u16), out f32 or bf16
// BM=BN=128, BK=64, 256 threads (4 waves, 2x2 of 64x64), mfma 16x16x32 bf16.
// LDS fragment-ordered per buffer: slot s = mt*2+ks (16 slots x 1KB); within slot lane-major 16B.
// Fragment: lane l -> row = mt*16 + (l&15), k = ks*32 + (l>>4)*8 + j.
// Schedule: STAGE(next) issued BEFORE compute(cur); one __syncthreads per K-step
// (its vmcnt(0) drain lands after the MFMA work -> load latency overlapped).
template<int BIAS /*0 none,1 col,2 row*/, int ACT, int OUTF32, int RES>
__global__ __launch_bounds__(256, 2) void gemm_nt(
    const u16* __restrict__ A, long sA,
    const u16* __restrict__ B, long sB,
    const float* __restrict__ bias,
    const float* __restrict__ res, long sRes,
    void* __restrict__ Cv, long sC,
    int ldA, int ldB, int ldC, int K, float scale)
{
    __shared__ u16 Al[16384];   // 2 buffers x 8192
    __shared__ u16 Bl[16384];
    const int tid = threadIdx.x;

    // ---- bijective XCD swizzle of the linearized block index (all grids %8==0) ----
    const int nx = gridDim.x, ny = gridDim.y;
    const int nwg = nx * ny * (int)gridDim.z;
    int orig = blockIdx.x + nx * (blockIdx.y + ny * blockIdx.z);
    int wg = ((nwg & 7) == 0) ? ((orig & 7) * (nwg >> 3) + (orig >> 3)) : orig;
    const int bx = wg % nx;
    const int tmp = wg / nx;
    const int by = tmp % ny;
    const int bz = tmp / ny;

    const int m0 = by * 128;
    const int n0 = bx * 128;
    A += (long)bz * sA;
    B += (long)bz * sB;
    const int l = tid & 63;
    const int w = tid >> 6;
    const int wr = w >> 1, wc = w & 1;

    // per-lane pre-swizzled global base (fragment-order source)
    const int fr = l & 15;        // row within 16-row fragment
    const int fk = (l >> 4) * 8;  // k offset within 32-wide k-slice
    const u16* gA = A + (long)(m0 + w * 32 + fr) * ldA + fk;
    const u16* gB = B + (long)(n0 + w * 32 + fr) * ldB + fk;

    f32x4 acc[4][4] = {};

#define STAGE(buf, kof)                                                              \
    {                                                                                \
        u16* la = &Al[(buf) * 8192 + w * 2048];                                      \
        u16* lb = &Bl[(buf) * 8192 + w * 2048];                                      \
        _Pragma("unroll")                                                            \
        for (int q = 0; q < 4; q++) {                                                \
            const long ka = (kof) + (q & 1) * 32 + (long)(q >> 1) * 16 * ldA;        \
            const long kb = (kof) + (q & 1) * 32 + (long)(q >> 1) * 16 * ldB;        \
            __builtin_amdgcn_global_load_lds(                                        \
                (const __attribute__((address_space(1))) u32*)(gA + ka),             \
                (__attribute__((address_space(3))) u32*)(la + q * 512), 16, 0, 0);   \
            __builtin_amdgcn_global_load_lds(                                        \
                (const __attribute__((address_space(1))) u32*)(gB + kb),             \
                (__attribute__((address_space(3))) u32*)(lb + q * 512), 16, 0, 0);   \
        }                                                                            \
    }

#define COMPUTE(buf)                                                                 \
    {                                                                                \
        _Pragma("unroll")                                                            \
        for (int ks = 0; ks < 2; ks++) {                                             \
            bf16x8 af[4], bfr[4];                                                    \
            _Pragma("unroll")                                                        \
            for (int t = 0; t < 4; t++) {                                            \
                af[t]  = *reinterpret_cast<const bf16x8*>(                           \
                    &Al[(buf) * 8192 + ((wr * 4 + t) * 2 + ks) * 512 + l * 8]);      \
                bfr[t] = *reinterpret_cast<const bf16x8*>(                           \
                    &Bl[(buf) * 8192 + ((wc * 4 + t) * 2 + ks) * 512 + l * 8]);      \
            }                                                                        \
            _Pragma("unroll")                                                        \
            for (int mt = 0; mt < 4; mt++)                                           \
                _Pragma("unroll")                                                    \
                for (int nt = 0; nt < 4; nt++)                                       \
                    acc[mt][nt] = __builtin_amdgcn_mfma_f32_16x16x32_bf16(           \
                        af[mt], bfr[nt], acc[mt][nt], 0, 0, 0);                      \
        }                                                                            \
    }

    STAGE(0, 0);
    __syncthreads();          // drain prologue loads
    int cur = 0;
    for (int k0 = 64; k0 < K; k0 += 64) {
        STAGE(cur ^ 1, k0);   // issue next tile (async, in flight during compute)
        COMPUTE(cur);
        __syncthreads();      // drains vmcnt(0): next buffer ready; orders reads vs overwrite
        cur ^= 1;
    }
    COMPUTE(cur);
#undef STAGE
#undef COMPUTE

    // epilogue: D col=l&15, row=(l>>4)*4+reg (m89-verified layout)
    const int lr = (l >> 4) * 4;
    const int lc = l & 15;
    #pragma unroll
    for (int mt = 0; mt < 4; mt++) {
        #pragma unroll
        for (int i = 0; i < 4; i++) {
            const int row = m0 + wr * 64 + mt * 16 + lr + i;
            #pragma unroll
            for (int nt = 0; nt < 4; nt++) {
                const int col = n0 + wc * 64 + nt * 16 + lc;
                float v = acc[mt][nt][i] * scale;
                if (BIAS == 1) v += bias[col];
                if (BIAS == 2) v += bias[row];
                if (ACT) v = fmaxf(v, 0.0f);
                if (RES) v += res[(long)bz * sRes + (long)row * ldC + col];
                const long ci = (long)bz * sC + (long)row * ldC + col;
                if (OUTF32) ((float*)Cv)[ci] = v;
                else        ((u16*)Cv)[ci] = f2b(v);
            }
        }
    }
}

// ------- row softmax: 1024 f32 in -> 1024 bf16 written IN-PLACE (row stride 2048 u16) -------
__global__ __launch_bounds__(256) void k_softmax(float* __restrict__ sc) {
    __shared__ float red[8];
    const int r = blockIdx.x;
    const int t = threadIdx.x;
    const int w = t >> 6;
    float* p = sc + (long)r * 1024;
    f32x4 v = reinterpret_cast<const f32x4*>(p)[t];
    float m = fmaxf(fmaxf(v.x, v.y), fmaxf(v.z, v.w));
    #pragma unroll
    for (int d = 32; d >= 1; d >>= 1) m = fmaxf(m, __shfl_xor(m, d));
    if ((t & 63) == 0) red[w] = m;
    __syncthreads();
    m = fmaxf(fmaxf(red[0], red[1]), fmaxf(red[2], red[3]));
    f32x4 e;
    e.x = __expf(v.x - m); e.y = __expf(v.y - m);
    e.z = __expf(v.z - m); e.w = __expf(v.w - m);
    float s = e.x + e.y + e.z + e.w;
    #pragma unroll
    for (int d = 32; d >= 1; d >>= 1) s += __shfl_xor(s, d);
    if ((t & 63) == 0) red[4 + w] = s;
    __syncthreads();
    s = red[4] + red[5] + red[6] + red[7];
    const float inv = 1.0f / s;
    ushort4 o;
    o.x = f2b(e.x * inv); o.y = f2b(e.y * inv);
    o.z = f2b(e.z * inv); o.w = f2b(e.w * inv);
    reinterpret_cast<ushort4*>(reinterpret_cast<u16*>(sc) + (long)r * 2048)[t] = o;
}

// ---------------- LayerNorm over D=512, one wave per row ----------------
__global__ __launch_bounds__(256) void k_layernorm(const float* __restrict__ in,
                                                   const float* __restrict__ g,
                                                   const float* __restrict__ be,
                                                   float* __restrict__ of,
                                                   u16* __restrict__ ob) {
    const int w = threadIdx.x >> 6;
    const int l = threadIdx.x & 63;
    const long row = (long)blockIdx.x * 4 + w;
    const float* p = in + row * 512;
    f32x4 v0 = *reinterpret_cast<const f32x4*>(p + l * 4);
    f32x4 v1 = *reinterpret_cast<const f32x4*>(p + 256 + l * 4);
    float s = v0.x + v0.y + v0.z + v0.w + v1.x + v1.y + v1.z + v1.w;
    float q = v0.x * v0.x + v0.y * v0.y + v0.z * v0.z + v0.w * v0.w
            + v1.x * v1.x + v1.y * v1.y + v1.z * v1.z + v1.w * v1.w;
    #pragma unroll
    for (int d = 32; d >= 1; d >>= 1) { s += __shfl_xor(s, d); q += __shfl_xor(q, d); }
    const float mean = s * (1.0f / 512.0f);
    const float var = q * (1.0f / 512.0f) - mean * mean;
    const float inv = rsqrtf(var + 1e-5f);
    f32x4 ga = *reinterpret_cast<const f32x4*>(g + l * 4);
    f32x4 gb = *reinterpret_cast<const f32x4*>(g + 256 + l * 4);
    f32x4 ba = *reinterpret_cast<const f32x4*>(be + l * 4);
    f32x4 bb = *reinterpret_cast<const f32x4*>(be + 256 + l * 4);
    f32x4 o0 = (v0 - mean) * inv * ga + ba;
    f32x4 o1 = (v1 - mean) * inv * gb + bb;
    *reinterpret_cast<f32x4*>(of + row * 512 + l * 4) = o0;
    *reinterpret_cast<f32x4*>(of + row * 512 + 256 + l * 4) = o1;
    if (ob) {
        ushort4 p0, p1;
        p0.x = f2b(o0.x); p0.y = f2b(o0.y); p0.z = f2b(o0.z); p0.w = f2b(o0.w);
        p1.x = f2b(o1.x); p1.y = f2b(o1.y); p1.z = f2b(o1.z); p1.w = f2b(o1.w);
        *reinterpret_cast<ushort4*>(ob + row * 512 + l * 4) = p0;
        *reinterpret_cast<ushort4*>(ob + row * 512 + 256 + l * 4) = p1;
    }
}

extern "C" void kernel_launch(void* const* d_in, const int* in_sizes, int n_in,
                              void* d_out, int out_size, void* d_ws, size_t ws_size,
                              hipStream_t stream) {
    const float* x   = (const float*)d_in[0];
    const float* Wq  = (const float*)d_in[1];
    const float* bq  = (const float*)d_in[2];
    const float* Wk  = (const float*)d_in[3];
    const float* bk  = (const float*)d_in[4];
    const float* Wv  = (const float*)d_in[5];
    const float* bv  = (const float*)d_in[6];
    const float* Wo  = (const float*)d_in[7];
    const float* bo  = (const float*)d_in[8];
    const float* g0  = (const float*)d_in[9];
    const float* be0 = (const float*)d_in[10];
    const float* W1  = (const float*)d_in[11];
    const float* b1  = (const float*)d_in[12];
    const float* W2  = (const float*)d_in[13];
    const float* b2  = (const float*)d_in[14];
    const float* g1  = (const float*)d_in[15];
    const float* be1 = (const float*)d_in[16];
    float* out = (float*)d_out;

    // ---- workspace layout, peak 194.0 MB ----
    char* ws = (char*)d_ws;
    u16*   xb     = (u16*)(ws + 0);            // [8192,512] bf16, 8.4 MB
    u16*   Wqb    = (u16*)(ws + 8388608);      // [Wq;Wk] contiguous [8192,512] bf16
    u16*   Wkb    = (u16*)(ws + 12582912);
    u16*   Wvb    = (u16*)(ws + 16777216);
    u16*   Wob    = (u16*)(ws + 20971520);
    u16*   W1b    = (u16*)(ws + 25165824);
    u16*   W2b    = (u16*)(ws + 25690112);
    // R1+R2 [26214400 .. 160432128): fused QK output [8192,8192] bf16 (Q cols 0..4095, K cols 4096..8191)
    u16*   QKb    = (u16*)(ws + 26214400);
    u16*   VTb    = QKb;                       // [8][4096,1024] bf16 into R1 (QK dead after scores)
    float* hsum   = (float*)(ws + 26214400);   // [8192,512] f32 (VT dead after PV)
    float* hf     = (float*)(ws + 42991616);
    u16*   hb     = (u16*)(ws + 59768832);
    u16*   ff1b   = (u16*)(ws + 68157440);
    float* t2     = (float*)(ws + 76546048);
    u16*   sdpab  = (u16*)(ws + 93323264);     // [8][1024,4096] bf16 into R2
    // R3 [160432128 .. 193986560): scores f32, attn bf16 in-place (ld 2048)
    float* scores = (float*)(ws + 160432128);
    u16*   attnb  = (u16*)scores;
    float* bqk    = (float*)(ws + 160432128);  // [bq;bk] 32KB, dead once scores GEMM writes

    // bias concat for fused QK projection (region is dead until scores GEMM)
    hipMemcpyAsync(bqk,        bq, 4096 * 4, hipMemcpyDeviceToDevice, stream);
    hipMemcpyAsync(bqk + 4096, bk, 4096 * 4, hipMemcpyDeviceToDevice, stream);

    // bf16 conversions
    k_convert<<<4096, 256, 0, stream>>>(x,  xb,  1048576);
    k_convert<<<2048, 256, 0, stream>>>(Wq, Wqb, 524288);
    k_convert<<<2048, 256, 0, stream>>>(Wk, Wkb, 524288);
    k_convert<<<2048, 256, 0, stream>>>(Wv, Wvb, 524288);
    k_convert<<<2048, 256, 0, stream>>>(Wo, Wob, 524288);
    k_convert<<<256,  256, 0, stream>>>(W1, W1b, 65536);
    k_convert<<<256,  256, 0, stream>>>(W2, W2b, 65536);

    const float scl = 0.044194173824159216f; // 1/sqrt(512)

    // [Q|K] = x·[Wq;Wk]^T + [bq;bk]   [8192,8192], ldC=8192
    gemm_nt<1,0,0,0><<<dim3(64,64,1), 256, 0, stream>>>(xb,0, Wqb,0, bqk, nullptr,0, QKb,0, 512,512,8192, 512, 1.0f);
    // scores[b] = (Q[b]·K[b]^T)/sqrt(512)  f32 [8][1024,1024]
    gemm_nt<0,0,1,0><<<dim3(8,8,8), 256, 0, stream>>>(QKb,8388608, QKb+4096,8388608, nullptr, nullptr,0, scores,1048576, 8192,8192,1024, 4096, scl);
    // attn = softmax(scores) -> bf16 in-place (row stride 2048)
    k_softmax<<<8192, 256, 0, stream>>>(scores);
    // V^T[b] = Wv·x[b]^T + bv(row)   [8][4096,1024]  (into dead Q region)
    gemm_nt<2,0,0,0><<<dim3(8,32,8), 256, 0, stream>>>(Wvb,0, xb,524288, bv, nullptr,0, VTb,4194304, 512,512,1024, 512, 1.0f);
    // sdpa[b] = attn[b]·(V^T[b])^T   [8][1024,4096]  (into dead K region)
    gemm_nt<0,0,0,0><<<dim3(32,8,8), 256, 0, stream>>>(attnb,2097152, VTb,4194304, nullptr, nullptr,0, sdpab,4194304, 2048,1024,4096, 1024, 1.0f);
    // hsum = sdpa·Wo^T + bo + x   f32 [8192,512]  (into dead VT region)
    gemm_nt<1,0,1,1><<<dim3(4,64,1), 256, 0, stream>>>(sdpab,0, Wob,0, bo, x,0, hsum,0, 4096,4096,512, 4096, 1.0f);
    // h = LN(hsum) -> f32 + bf16
    k_layernorm<<<2048, 256, 0, stream>>>(hsum, g0, be0, hf, hb);
    // ff1 = relu(h·W1^T + b1) bf16
    gemm_nt<1,1,0,0><<<dim3(4,64,1), 256, 0, stream>>>(hb,0, W1b,0, b1, nullptr,0, ff1b,0, 512,512,512, 512, 1.0f);
    // t2 = ff1·W2^T + b2 + h  f32
    gemm_nt<1,0,1,1><<<dim3(4,64,1), 256, 0, stream>>>(ff1b,0, W2b,0, b2, hf,0, t2,0, 512,512,512, 512, 1.0f);
    // out = LN(t2)
    k_layernorm<<<2048, 256, 0, stream>>>(t2, g1, be1, out, nullptr);
}

// Round 5
// 669.080 us; speedup vs baseline: 1.2898x; 1.2898x over previous
//
#include <hip/hip_runtime.h>

typedef unsigned short u16;
typedef unsigned int u32;
typedef float f32x4 __attribute__((ext_vector_type(4)));
typedef __bf16 bf16x8 __attribute__((ext_vector_type(8)));

__device__ __forceinline__ u16 f2b(float f) {
    u32 b = __builtin_bit_cast(u32, f);
    b = b + 0x7FFFu + ((b >> 16) & 1u);
    return (u16)(b >> 16);
}

// ---------------- fp32 -> bf16 convert (4 elems/thread) ----------------
__global__ __launch_bounds__(256) void k_convert(const float* __restrict__ in,
                                                 u16* __restrict__ out, int n4) {
    int i = blockIdx.x * 256 + threadIdx.x;
    if (i >= n4) return;
    f32x4 v = reinterpret_cast<const f32x4*>(in)[i];
    ushort4 o;
    o.x = f2b(v.x); o.y = f2b(v.y); o.z = f2b(v.z); o.w = f2b(v.w);
    reinterpret_cast<ushort4*>(out)[i] = o;
}

// ============ 128^2 NT bf16 GEMM — round-3 proven structure (single buffer) + XCD swizzle ======
// C[m,n] = scale * sum_k A[m,k]*B[n,k]  (+bias)(+relu)(+res)
// BM=BN=128, BK=64, 256 threads (4 waves 2x2), mfma 16x16x32 bf16. 32 KB LDS -> 3 blocks/CU.
// LDS fragment-ordered: slot s=mt*2+ks (16 x 1KB); lane-major 16B. 0 bank conflicts (measured r3).
template<int BIAS /*0 none,1 col,2 row*/, int ACT, int OUTF32, int RES>
__global__ __launch_bounds__(256, 2) void gemm_nt(
    const u16* __restrict__ A, long sA,
    const u16* __restrict__ B, long sB,
    const float* __restrict__ bias,
    const float* __restrict__ res, long sRes,
    void* __restrict__ Cv, long sC,
    int ldA, int ldB, int ldC, int K, float scale)
{
    __shared__ u16 Al[8192];
    __shared__ u16 Bl[8192];
    const int tid = threadIdx.x;

    // bijective XCD swizzle (all grids here have nwg % 8 == 0)
    const int nx = gridDim.x, ny = gridDim.y;
    const int nwg = nx * ny * (int)gridDim.z;
    int orig = blockIdx.x + nx * (blockIdx.y + ny * blockIdx.z);
    int wg = ((nwg & 7) == 0) ? ((orig & 7) * (nwg >> 3) + (orig >> 3)) : orig;
    const int bx = wg % nx;
    const int tmp = wg / nx;
    const int by = tmp % ny;
    const int bz = tmp / ny;

    const int m0 = by * 128;
    const int n0 = bx * 128;
    A += (long)bz * sA;
    B += (long)bz * sB;
    const int l = tid & 63;
    const int w = tid >> 6;
    const int wr = w >> 1, wc = w & 1;

    const int fr = l & 15;
    const int fk = (l >> 4) * 8;
    const u16* gA = A + (long)(m0 + w * 32 + fr) * ldA + fk;
    const u16* gB = B + (long)(n0 + w * 32 + fr) * ldB + fk;
    u16* lA = &Al[w * 2048];
    u16* lB = &Bl[w * 2048];

    f32x4 acc[4][4] = {};

    for (int k0 = 0; k0 < K; k0 += 64) {
        __syncthreads();
        #pragma unroll
        for (int q = 0; q < 4; q++) {
            const long ka = k0 + (q & 1) * 32 + (long)(q >> 1) * 16 * ldA;
            const long kb = k0 + (q & 1) * 32 + (long)(q >> 1) * 16 * ldB;
            __builtin_amdgcn_global_load_lds(
                (const __attribute__((address_space(1))) u32*)(gA + ka),
                (__attribute__((address_space(3))) u32*)(lA + q * 512), 16, 0, 0);
            __builtin_amdgcn_global_load_lds(
                (const __attribute__((address_space(1))) u32*)(gB + kb),
                (__attribute__((address_space(3))) u32*)(lB + q * 512), 16, 0, 0);
        }
        __syncthreads();
        #pragma unroll
        for (int ks = 0; ks < 2; ks++) {
            bf16x8 af[4], bfr[4];
            #pragma unroll
            for (int t = 0; t < 4; t++) {
                af[t]  = *reinterpret_cast<const bf16x8*>(&Al[((wr * 4 + t) * 2 + ks) * 512 + l * 8]);
                bfr[t] = *reinterpret_cast<const bf16x8*>(&Bl[((wc * 4 + t) * 2 + ks) * 512 + l * 8]);
            }
            #pragma unroll
            for (int mt = 0; mt < 4; mt++)
                #pragma unroll
                for (int nt = 0; nt < 4; nt++)
                    acc[mt][nt] = __builtin_amdgcn_mfma_f32_16x16x32_bf16(af[mt], bfr[nt], acc[mt][nt], 0, 0, 0);
        }
    }

    const int lr = (l >> 4) * 4;
    const int lc = l & 15;
    #pragma unroll
    for (int mt = 0; mt < 4; mt++) {
        #pragma unroll
        for (int i = 0; i < 4; i++) {
            const int row = m0 + wr * 64 + mt * 16 + lr + i;
            #pragma unroll
            for (int nt = 0; nt < 4; nt++) {
                const int col = n0 + wc * 64 + nt * 16 + lc;
                float v = acc[mt][nt][i] * scale;
                if (BIAS == 1) v += bias[col];
                if (BIAS == 2) v += bias[row];
                if (ACT) v = fmaxf(v, 0.0f);
                if (RES) v += res[(long)bz * sRes + (long)row * ldC + col];
                const long ci = (long)bz * sC + (long)row * ldC + col;
                if (OUTF32) ((float*)Cv)[ci] = v;
                else        ((u16*)Cv)[ci] = f2b(v);
            }
        }
    }
}

// ============ 256^2 NT bf16 GEMM — T3/T4: dbuf + counted-drain + raw barriers ============
// 512 threads (8 waves 2M x 4N), BM=BN=256, BK=64. Per-wave out 128x64 -> acc[8][4] f32x4.
// LDS dynamic 128 KB: A[2][16384 u16] then B[2][16384 u16]; fragment-ordered linear
// (slot s = mt*2+ks, 32 slots x 1KB, lane-major 16B) -> conflict-free, gload_lds-compatible.
// Stage of tile into buf: 8 loads/thread (4 A + 4 B), phase p stages slot s=p*8+w of each.
// Schedule per K-tile t: vmcnt(0) [waits ONLY tile-t loads, issued one full iter ago ->
// ~64 MFMAs of cover, never drains same-phase loads] ; raw s_barrier (+sched_barrier pin);
// 4 phases of { 8x ds_read_b128 ; 2x gload_lds(tile t+1 -> buf^1) ; setprio(1) 16 MFMA setprio(0) }.
// Race notes: stage(t+1) writes buf^1, read last in iter t-1; iter-t top barrier separates.
// ds_reads complete before each wave's barrier arrival (consumed by MFMAs via lgkm dep).
template<int BIAS /*0,1 col,2 row*/, int OUTF32>
__global__ __launch_bounds__(512, 2) void gemm_nt256(
    const u16* __restrict__ A, long sA,
    const u16* __restrict__ B, long sB,
    const float* __restrict__ bias,
    void* __restrict__ Cv, long sC,
    int ldA, int ldB, int ldC, int K, float scale)
{
    extern __shared__ u16 lds[];   // 65536 u16 = 128 KB
    const int tid = threadIdx.x;

    const int nx = gridDim.x, ny = gridDim.y;
    const int nwg = nx * ny * (int)gridDim.z;
    int orig = blockIdx.x + nx * (blockIdx.y + ny * blockIdx.z);
    int wg = ((nwg & 7) == 0) ? ((orig & 7) * (nwg >> 3) + (orig >> 3)) : orig;
    const int bx = wg % nx;
    const int tmp = wg / nx;
    const int by = tmp % ny;
    const int bz = tmp / ny;

    const int m0 = by * 256;
    const int n0 = bx * 256;
    A += (long)bz * sA;
    B += (long)bz * sB;
    const int l = tid & 63;
    const int w = tid >> 6;          // 0..7
    const int wr = w >> 2, wc = w & 3;

    const int fr = l & 15;
    const int fk = (l >> 4) * 8;
    // stage decomposition: slot s = p*8 + w  ->  mt = p*4 + (w>>1), ks = w&1
    const int ksS = w & 1;
    const int mtS = w >> 1;
    const u16* gA = A + (long)(m0 + mtS * 16 + fr) * ldA + ksS * 32 + fk;
    const u16* gB = B + (long)(n0 + mtS * 16 + fr) * ldB + ksS * 32 + fk;

    f32x4 acc[8][4] = {};
    const int nt = K >> 6;

#define STAGE2(buf, k0, p)                                                                   \
    {                                                                                        \
        __builtin_amdgcn_global_load_lds(                                                    \
            (const __attribute__((address_space(1))) u32*)(gA + (long)(p) * 64 * ldA + (k0)),\
            (__attribute__((address_space(3))) u32*)(lds + (buf) * 16384 + ((p) * 8 + w) * 512), 16, 0, 0); \
        __builtin_amdgcn_global_load_lds(                                                    \
            (const __attribute__((address_space(1))) u32*)(gB + (long)(p) * 64 * ldB + (k0)),\
            (__attribute__((address_space(3))) u32*)(lds + 32768 + (buf) * 16384 + ((p) * 8 + w) * 512), 16, 0, 0); \
    }

#define PHASE(buf, p, DOSTAGE, k1)                                                           \
    {                                                                                        \
        const int ksc = (p) & 1, mh = (p) >> 1;                                              \
        bf16x8 af[4], bfv[4];                                                                \
        _Pragma("unroll")                                                                    \
        for (int t4 = 0; t4 < 4; t4++) {                                                     \
            af[t4]  = *reinterpret_cast<const bf16x8*>(                                      \
                lds + (buf) * 16384 + ((wr * 8 + mh * 4 + t4) * 2 + ksc) * 512 + l * 8);     \
            bfv[t4] = *reinterpret_cast<const bf16x8*>(                                      \
                lds + 32768 + (buf) * 16384 + ((wc * 4 + t4) * 2 + ksc) * 512 + l * 8);      \
        }                                                                                    \
        if (DOSTAGE) STAGE2((buf) ^ 1, k1, p);                                               \
        __builtin_amdgcn_s_setprio(1);                                                       \
        _Pragma("unroll")                                                                    \
        for (int mi = 0; mi < 4; mi++)                                                       \
            _Pragma("unroll")                                                                \
            for (int ni = 0; ni < 4; ni++)                                                   \
                acc[mh * 4 + mi][ni] = __builtin_amdgcn_mfma_f32_16x16x32_bf16(              \
                    af[mi], bfv[ni], acc[mh * 4 + mi][ni], 0, 0, 0);                         \
        __builtin_amdgcn_s_setprio(0);                                                       \
    }

    // prologue: stage tile 0 into buf 0
    STAGE2(0, 0, 0); STAGE2(0, 0, 1); STAGE2(0, 0, 2); STAGE2(0, 0, 3);

    for (int t = 0; t < nt; ++t) {
        const int buf = t & 1;
        asm volatile("s_waitcnt vmcnt(0)" ::: "memory");  // tile-t loads (issued last iter) done
        __builtin_amdgcn_s_barrier();                     // all waves' tile-t loads done
        __builtin_amdgcn_sched_barrier(0);                // pin: no ds_read hoists above barrier
        const bool st = (t + 1) < nt;
        const int k1 = (t + 1) << 6;
        PHASE(buf, 0, st, k1);
        PHASE(buf, 1, st, k1);
        PHASE(buf, 2, st, k1);
        PHASE(buf, 3, st, k1);
    }
#undef STAGE2
#undef PHASE

    const int lr = (l >> 4) * 4;
    const int lc = l & 15;
    #pragma unroll
    for (int mf = 0; mf < 8; mf++) {
        #pragma unroll
        for (int i = 0; i < 4; i++) {
            const int row = m0 + wr * 128 + mf * 16 + lr + i;
            #pragma unroll
            for (int ni = 0; ni < 4; ni++) {
                const int col = n0 + wc * 64 + ni * 16 + lc;
                float v = acc[mf][ni][i] * scale;
                if (BIAS == 1) v += bias[col];
                if (BIAS == 2) v += bias[row];
                const long ci = (long)bz * sC + (long)row * ldC + col;
                if (OUTF32) ((float*)Cv)[ci] = v;
                else        ((u16*)Cv)[ci] = f2b(v);
            }
        }
    }
}

// ------- row softmax: 1024 f32 in -> 1024 bf16 written IN-PLACE (row stride 2048 u16) -------
__global__ __launch_bounds__(256) void k_softmax(float* __restrict__ sc) {
    __shared__ float red[8];
    const int r = blockIdx.x;
    const int t = threadIdx.x;
    const int w = t >> 6;
    float* p = sc + (long)r * 1024;
    f32x4 v = reinterpret_cast<const f32x4*>(p)[t];
    float m = fmaxf(fmaxf(v.x, v.y), fmaxf(v.z, v.w));
    #pragma unroll
    for (int d = 32; d >= 1; d >>= 1) m = fmaxf(m, __shfl_xor(m, d));
    if ((t & 63) == 0) red[w] = m;
    __syncthreads();
    m = fmaxf(fmaxf(red[0], red[1]), fmaxf(red[2], red[3]));
    f32x4 e;
    e.x = __expf(v.x - m); e.y = __expf(v.y - m);
    e.z = __expf(v.z - m); e.w = __expf(v.w - m);
    float s = e.x + e.y + e.z + e.w;
    #pragma unroll
    for (int d = 32; d >= 1; d >>= 1) s += __shfl_xor(s, d);
    if ((t & 63) == 0) red[4 + w] = s;
    __syncthreads();
    s = red[4] + red[5] + red[6] + red[7];
    const float inv = 1.0f / s;
    ushort4 o;
    o.x = f2b(e.x * inv); o.y = f2b(e.y * inv);
    o.z = f2b(e.z * inv); o.w = f2b(e.w * inv);
    reinterpret_cast<ushort4*>(reinterpret_cast<u16*>(sc) + (long)r * 2048)[t] = o;
}

// ---------------- LayerNorm over D=512, one wave per row ----------------
__global__ __launch_bounds__(256) void k_layernorm(const float* __restrict__ in,
                                                   const float* __restrict__ g,
                                                   const float* __restrict__ be,
                                                   float* __restrict__ of,
                                                   u16* __restrict__ ob) {
    const int w = threadIdx.x >> 6;
    const int l = threadIdx.x & 63;
    const long row = (long)blockIdx.x * 4 + w;
    const float* p = in + row * 512;
    f32x4 v0 = *reinterpret_cast<const f32x4*>(p + l * 4);
    f32x4 v1 = *reinterpret_cast<const f32x4*>(p + 256 + l * 4);
    float s = v0.x + v0.y + v0.z + v0.w + v1.x + v1.y + v1.z + v1.w;
    float q = v0.x * v0.x + v0.y * v0.y + v0.z * v0.z + v0.w * v0.w
            + v1.x * v1.x + v1.y * v1.y + v1.z * v1.z + v1.w * v1.w;
    #pragma unroll
    for (int d = 32; d >= 1; d >>= 1) { s += __shfl_xor(s, d); q += __shfl_xor(q, d); }
    const float mean = s * (1.0f / 512.0f);
    const float var = q * (1.0f / 512.0f) - mean * mean;
    const float inv = rsqrtf(var + 1e-5f);
    f32x4 ga = *reinterpret_cast<const f32x4*>(g + l * 4);
    f32x4 gb = *reinterpret_cast<const f32x4*>(g + 256 + l * 4);
    f32x4 ba = *reinterpret_cast<const f32x4*>(be + l * 4);
    f32x4 bb = *reinterpret_cast<const f32x4*>(be + 256 + l * 4);
    f32x4 o0 = (v0 - mean) * inv * ga + ba;
    f32x4 o1 = (v1 - mean) * inv * gb + bb;
    *reinterpret_cast<f32x4*>(of + row * 512 + l * 4) = o0;
    *reinterpret_cast<f32x4*>(of + row * 512 + 256 + l * 4) = o1;
    if (ob) {
        ushort4 p0, p1;
        p0.x = f2b(o0.x); p0.y = f2b(o0.y); p0.z = f2b(o0.z); p0.w = f2b(o0.w);
        p1.x = f2b(o1.x); p1.y = f2b(o1.y); p1.z = f2b(o1.z); p1.w = f2b(o1.w);
        *reinterpret_cast<ushort4*>(ob + row * 512 + l * 4) = p0;
        *reinterpret_cast<ushort4*>(ob + row * 512 + 256 + l * 4) = p1;
    }
}

extern "C" void kernel_launch(void* const* d_in, const int* in_sizes, int n_in,
                              void* d_out, int out_size, void* d_ws, size_t ws_size,
                              hipStream_t stream) {
    const float* x   = (const float*)d_in[0];
    const float* Wq  = (const float*)d_in[1];
    const float* bq  = (const float*)d_in[2];
    const float* Wk  = (const float*)d_in[3];
    const float* bk  = (const float*)d_in[4];
    const float* Wv  = (const float*)d_in[5];
    const float* bv  = (const float*)d_in[6];
    const float* Wo  = (const float*)d_in[7];
    const float* bo  = (const float*)d_in[8];
    const float* g0  = (const float*)d_in[9];
    const float* be0 = (const float*)d_in[10];
    const float* W1  = (const float*)d_in[11];
    const float* b1  = (const float*)d_in[12];
    const float* W2  = (const float*)d_in[13];
    const float* b2  = (const float*)d_in[14];
    const float* g1  = (const float*)d_in[15];
    const float* be1 = (const float*)d_in[16];
    float* out = (float*)d_out;

    // ---- workspace layout, peak 194.0 MB ----
    char* ws = (char*)d_ws;
    u16*   xb     = (u16*)(ws + 0);            // [8192,512] bf16
    u16*   Wqb    = (u16*)(ws + 8388608);      // [Wq;Wk] contiguous [8192,512] bf16
    u16*   Wkb    = (u16*)(ws + 12582912);
    u16*   Wvb    = (u16*)(ws + 16777216);
    u16*   Wob    = (u16*)(ws + 20971520);
    u16*   W1b    = (u16*)(ws + 25165824);
    u16*   W2b    = (u16*)(ws + 25690112);
    // R1+R2 [26214400 .. 160432128): fused QK output [8192,8192] bf16 (Q cols 0..4095, K 4096..8191)
    u16*   QKb    = (u16*)(ws + 26214400);
    u16*   VTb    = QKb;                       // [8][4096,1024] bf16 (QK dead after scores)
    float* hsum   = (float*)(ws + 26214400);   // [8192,512] f32 (VT dead after PV)
    float* hf     = (float*)(ws + 42991616);
    u16*   hb     = (u16*)(ws + 59768832);
    u16*   ff1b   = (u16*)(ws + 68157440);
    float* t2     = (float*)(ws + 76546048);
    u16*   sdpab  = (u16*)(ws + 93323264);     // [8][1024,4096] bf16
    // R3 [160432128 .. 193986560): scores f32, attn bf16 in-place (ld 2048)
    float* scores = (float*)(ws + 160432128);
    u16*   attnb  = (u16*)scores;
    float* bqk    = (float*)(ws + 160432128);  // [bq;bk] 32KB, dead once scores GEMM writes

    hipMemcpyAsync(bqk,        bq, 4096 * 4, hipMemcpyDeviceToDevice, stream);
    hipMemcpyAsync(bqk + 4096, bk, 4096 * 4, hipMemcpyDeviceToDevice, stream);

    k_convert<<<4096, 256, 0, stream>>>(x,  xb,  1048576);
    k_convert<<<2048, 256, 0, stream>>>(Wq, Wqb, 524288);
    k_convert<<<2048, 256, 0, stream>>>(Wk, Wkb, 524288);
    k_convert<<<2048, 256, 0, stream>>>(Wv, Wvb, 524288);
    k_convert<<<2048, 256, 0, stream>>>(Wo, Wob, 524288);
    k_convert<<<256,  256, 0, stream>>>(W1, W1b, 65536);
    k_convert<<<256,  256, 0, stream>>>(W2, W2b, 65536);

    const float scl = 0.044194173824159216f; // 1/sqrt(512)
    const size_t LDS256 = 131072;

    // [Q|K] = x·[Wq;Wk]^T + [bq;bk]   [8192,8192]
    gemm_nt256<1,0><<<dim3(32,32,1), 512, LDS256, stream>>>(xb,0, Wqb,0, bqk, QKb,0, 512,512,8192, 512, 1.0f);
    // scores[b] = (Q[b]·K[b]^T)/sqrt(512)  f32 [8][1024,1024]
    gemm_nt256<0,1><<<dim3(4,4,8), 512, LDS256, stream>>>(QKb,8388608, QKb+4096,8388608, nullptr, scores,1048576, 8192,8192,1024, 4096, scl);
    // attn = softmax(scores) -> bf16 in-place (row stride 2048)
    k_softmax<<<8192, 256, 0, stream>>>(scores);
    // V^T[b] = Wv·x[b]^T + bv(row)   [8][4096,1024]
    gemm_nt256<2,0><<<dim3(4,16,8), 512, LDS256, stream>>>(Wvb,0, xb,524288, bv, VTb,4194304, 512,512,1024, 512, 1.0f);
    // sdpa[b] = attn[b]·(V^T[b])^T   [8][1024,4096]
    gemm_nt256<0,0><<<dim3(16,4,8), 512, LDS256, stream>>>(attnb,2097152, VTb,4194304, nullptr, sdpab,4194304, 2048,1024,4096, 1024, 1.0f);
    // hsum = sdpa·Wo^T + bo + x   f32 [8192,512]
    gemm_nt<1,0,1,1><<<dim3(4,64,1), 256, 0, stream>>>(sdpab,0, Wob,0, bo, x,0, hsum,0, 4096,4096,512, 4096, 1.0f);
    // h = LN(hsum) -> f32 + bf16
    k_layernorm<<<2048, 256, 0, stream>>>(hsum, g0, be0, hf, hb);
    // ff1 = relu(h·W1^T + b1) bf16
    gemm_nt<1,1,0,0><<<dim3(4,64,1), 256, 0, stream>>>(hb,0, W1b,0, b1, nullptr,0, ff1b,0, 512,512,512, 512, 1.0f);
    // t2 = ff1·W2^T + b2 + h  f32
    gemm_nt<1,0,1,1><<<dim3(4,64,1), 256, 0, stream>>>(ff1b,0, W2b,0, b2, hf,0, t2,0, 512,512,512, 512, 1.0f);
    // out = LN(t2)
    k_layernorm<<<2048, 256, 0, stream>>>(t2, g1, be1, out, nullptr);
}

// Round 6
// 640.987 us; speedup vs baseline: 1.3463x; 1.0438x over previous
//
#include <hip/hip_runtime.h>

typedef unsigned short u16;
typedef unsigned int u32;
typedef float f32x4 __attribute__((ext_vector_type(4)));
typedef __bf16 bf16x8 __attribute__((ext_vector_type(8)));

__device__ __forceinline__ u16 f2b(float f) {
    u32 b = __builtin_bit_cast(u32, f);
    b = b + 0x7FFFu + ((b >> 16) & 1u);
    return (u16)(b >> 16);
}

// ---------------- fp32 -> bf16 convert (4 elems/thread) ----------------
__global__ __launch_bounds__(256) void k_convert(const float* __restrict__ in,
                                                 u16* __restrict__ out, int n4) {
    int i = blockIdx.x * 256 + threadIdx.x;
    if (i >= n4) return;
    f32x4 v = reinterpret_cast<const f32x4*>(in)[i];
    ushort4 o;
    o.x = f2b(v.x); o.y = f2b(v.y); o.z = f2b(v.z); o.w = f2b(v.w);
    reinterpret_cast<ushort4*>(out)[i] = o;
}

// ============ 128^2 NT bf16 GEMM — round-3 proven structure (single buffer) + XCD swizzle ======
template<int BIAS /*0 none,1 col,2 row*/, int ACT, int OUTF32, int RES>
__global__ __launch_bounds__(256, 2) void gemm_nt(
    const u16* __restrict__ A, long sA,
    const u16* __restrict__ B, long sB,
    const float* __restrict__ bias,
    const float* __restrict__ res, long sRes,
    void* __restrict__ Cv, long sC,
    int ldA, int ldB, int ldC, int K, float scale)
{
    __shared__ u16 Al[8192];
    __shared__ u16 Bl[8192];
    const int tid = threadIdx.x;

    const int nx = gridDim.x, ny = gridDim.y;
    const int nwg = nx * ny * (int)gridDim.z;
    int orig = blockIdx.x + nx * (blockIdx.y + ny * blockIdx.z);
    int wg = ((nwg & 7) == 0) ? ((orig & 7) * (nwg >> 3) + (orig >> 3)) : orig;
    const int bx = wg % nx;
    const int tmp = wg / nx;
    const int by = tmp % ny;
    const int bz = tmp / ny;

    const int m0 = by * 128;
    const int n0 = bx * 128;
    A += (long)bz * sA;
    B += (long)bz * sB;
    const int l = tid & 63;
    const int w = tid >> 6;
    const int wr = w >> 1, wc = w & 1;

    const int fr = l & 15;
    const int fk = (l >> 4) * 8;
    const u16* gA = A + (long)(m0 + w * 32 + fr) * ldA + fk;
    const u16* gB = B + (long)(n0 + w * 32 + fr) * ldB + fk;
    u16* lA = &Al[w * 2048];
    u16* lB = &Bl[w * 2048];

    f32x4 acc[4][4] = {};

    for (int k0 = 0; k0 < K; k0 += 64) {
        __syncthreads();
        #pragma unroll
        for (int q = 0; q < 4; q++) {
            const long ka = k0 + (q & 1) * 32 + (long)(q >> 1) * 16 * ldA;
            const long kb = k0 + (q & 1) * 32 + (long)(q >> 1) * 16 * ldB;
            __builtin_amdgcn_global_load_lds(
                (const __attribute__((address_space(1))) u32*)(gA + ka),
                (__attribute__((address_space(3))) u32*)(lA + q * 512), 16, 0, 0);
            __builtin_amdgcn_global_load_lds(
                (const __attribute__((address_space(1))) u32*)(gB + kb),
                (__attribute__((address_space(3))) u32*)(lB + q * 512), 16, 0, 0);
        }
        __syncthreads();
        #pragma unroll
        for (int ks = 0; ks < 2; ks++) {
            bf16x8 af[4], bfr[4];
            #pragma unroll
            for (int t = 0; t < 4; t++) {
                af[t]  = *reinterpret_cast<const bf16x8*>(&Al[((wr * 4 + t) * 2 + ks) * 512 + l * 8]);
                bfr[t] = *reinterpret_cast<const bf16x8*>(&Bl[((wc * 4 + t) * 2 + ks) * 512 + l * 8]);
            }
            #pragma unroll
            for (int mt = 0; mt < 4; mt++)
                #pragma unroll
                for (int nt = 0; nt < 4; nt++)
                    acc[mt][nt] = __builtin_amdgcn_mfma_f32_16x16x32_bf16(af[mt], bfr[nt], acc[mt][nt], 0, 0, 0);
        }
    }

    const int lr = (l >> 4) * 4;
    const int lc = l & 15;
    #pragma unroll
    for (int mt = 0; mt < 4; mt++) {
        #pragma unroll
        for (int i = 0; i < 4; i++) {
            const int row = m0 + wr * 64 + mt * 16 + lr + i;
            #pragma unroll
            for (int nt = 0; nt < 4; nt++) {
                const int col = n0 + wc * 64 + nt * 16 + lc;
                float v = acc[mt][nt][i] * scale;
                if (BIAS == 1) v += bias[col];
                if (BIAS == 2) v += bias[row];
                if (ACT) v = fmaxf(v, 0.0f);
                if (RES) v += res[(long)bz * sRes + (long)row * ldC + col];
                const long ci = (long)bz * sC + (long)row * ldC + col;
                if (OUTF32) ((float*)Cv)[ci] = v;
                else        ((u16*)Cv)[ci] = f2b(v);
            }
        }
    }
}

// ============ big-tile NT bf16 GEMM — T3/T4 schedule, BM = 32*AM x BN = 256 ============
// 512 threads (8 waves 2M x 4N), BK=64. Per-wave out (AM*16) x 64 -> acc[AM][4] f32x4.
// AM=8: 256x256 tile, 128 KB LDS. AM=4: 128x256 tile, 96 KB LDS (for grids that need >=256 blocks).
// LDS (dynamic, u16): A[2][AM*2048] at 0, B[2][16384] at 2*AS. Fragment-ordered linear
// (slot s = mt*2+ks, 1KB lane-major 16B) -> conflict-free, gload_lds-compatible.
// Schedule per K-tile t: vmcnt(0) [waits tile-t loads, issued one full iter ago];
// raw s_barrier + sched_barrier; 4 phases of { ds_read_b128 x(AM/2+4) ; gload_lds(tile t+1) ;
// setprio(1) MFMA x(AM/2*4) setprio(0) }.  Same verified structure as round 5, AM-generalized.
template<int AM, int BIAS /*0,1 col,2 row*/, int OUTF32>
__global__ __launch_bounds__(512, 2) void gemm_nt256(
    const u16* __restrict__ A, long sA,
    const u16* __restrict__ B, long sB,
    const float* __restrict__ bias,
    void* __restrict__ Cv, long sC,
    int ldA, int ldB, int ldC, int K, float scale)
{
    extern __shared__ u16 lds[];
    constexpr int AS = AM * 2048;   // per-buffer A size in u16
    const int tid = threadIdx.x;

    const int nx = gridDim.x, ny = gridDim.y;
    const int nwg = nx * ny * (int)gridDim.z;
    int orig = blockIdx.x + nx * (blockIdx.y + ny * blockIdx.z);
    int wg = ((nwg & 7) == 0) ? ((orig & 7) * (nwg >> 3) + (orig >> 3)) : orig;
    const int bx = wg % nx;
    const int tmp = wg / nx;
    const int by = tmp % ny;
    const int bz = tmp / ny;

    const int m0 = by * (AM * 32);
    const int n0 = bx * 256;
    A += (long)bz * sA;
    B += (long)bz * sB;
    const int l = tid & 63;
    const int w = tid >> 6;          // 0..7
    const int wr = w >> 2, wc = w & 3;

    const int fr = l & 15;
    const int fk = (l >> 4) * 8;
    const int ksS = w & 1;
    const int mtS = w >> 1;
    const u16* gA = A + (long)(m0 + mtS * 16 + fr) * ldA + ksS * 32 + fk;
    const u16* gB = B + (long)(n0 + mtS * 16 + fr) * ldB + ksS * 32 + fk;

    f32x4 acc[AM][4] = {};
    const int nt = K >> 6;

#define STAGE2(buf, k1, p)                                                                   \
    {                                                                                        \
        if ((p) < AM / 2)                                                                    \
            __builtin_amdgcn_global_load_lds(                                                \
                (const __attribute__((address_space(1))) u32*)(gA + (long)(p) * 64 * ldA + (k1)),\
                (__attribute__((address_space(3))) u32*)(lds + (buf) * AS + ((p) * 8 + w) * 512), 16, 0, 0); \
        __builtin_amdgcn_global_load_lds(                                                    \
            (const __attribute__((address_space(1))) u32*)(gB + (long)(p) * 64 * ldB + (k1)),\
            (__attribute__((address_space(3))) u32*)(lds + 2 * AS + (buf) * 16384 + ((p) * 8 + w) * 512), 16, 0, 0); \
    }

#define PHASE(buf, p, DOSTAGE, k1)                                                           \
    {                                                                                        \
        const int ksc = (p) & 1, mh = (p) >> 1;                                              \
        bf16x8 af[AM / 2], bfv[4];                                                           \
        _Pragma("unroll")                                                                    \
        for (int t4 = 0; t4 < AM / 2; t4++)                                                  \
            af[t4] = *reinterpret_cast<const bf16x8*>(                                       \
                lds + (buf) * AS + ((wr * AM + mh * (AM / 2) + t4) * 2 + ksc) * 512 + l * 8);\
        _Pragma("unroll")                                                                    \
        for (int t4 = 0; t4 < 4; t4++)                                                       \
            bfv[t4] = *reinterpret_cast<const bf16x8*>(                                      \
                lds + 2 * AS + (buf) * 16384 + ((wc * 4 + t4) * 2 + ksc) * 512 + l * 8);     \
        if (DOSTAGE) STAGE2((buf) ^ 1, k1, p);                                               \
        __builtin_amdgcn_s_setprio(1);                                                       \
        _Pragma("unroll")                                                                    \
        for (int mi = 0; mi < AM / 2; mi++)                                                  \
            _Pragma("unroll")                                                                \
            for (int ni = 0; ni < 4; ni++)                                                   \
                acc[mh * (AM / 2) + mi][ni] = __builtin_amdgcn_mfma_f32_16x16x32_bf16(       \
                    af[mi], bfv[ni], acc[mh * (AM / 2) + mi][ni], 0, 0, 0);                  \
        __builtin_amdgcn_s_setprio(0);                                                       \
    }

    STAGE2(0, 0, 0); STAGE2(0, 0, 1); STAGE2(0, 0, 2); STAGE2(0, 0, 3);

    for (int t = 0; t < nt; ++t) {
        const int buf = t & 1;
        asm volatile("s_waitcnt vmcnt(0)" ::: "memory");
        __builtin_amdgcn_s_barrier();
        __builtin_amdgcn_sched_barrier(0);
        const bool st = (t + 1) < nt;
        const int k1 = (t + 1) << 6;
        PHASE(buf, 0, st, k1);
        PHASE(buf, 1, st, k1);
        PHASE(buf, 2, st, k1);
        PHASE(buf, 3, st, k1);
    }
#undef STAGE2
#undef PHASE

    const int lr = (l >> 4) * 4;
    const int lc = l & 15;
    #pragma unroll
    for (int mf = 0; mf < AM; mf++) {
        #pragma unroll
        for (int i = 0; i < 4; i++) {
            const int row = m0 + wr * (AM * 16) + mf * 16 + lr + i;
            #pragma unroll
            for (int ni = 0; ni < 4; ni++) {
                const int col = n0 + wc * 64 + ni * 16 + lc;
                float v = acc[mf][ni][i] * scale;
                if (BIAS == 1) v += bias[col];
                if (BIAS == 2) v += bias[row];
                const long ci = (long)bz * sC + (long)row * ldC + col;
                if (OUTF32) ((float*)Cv)[ci] = v;
                else        ((u16*)Cv)[ci] = f2b(v);
            }
        }
    }
}

// ------- row softmax: 1024 f32 in -> 1024 bf16 written IN-PLACE (row stride 2048 u16) -------
__global__ __launch_bounds__(256) void k_softmax(float* __restrict__ sc) {
    __shared__ float red[8];
    const int r = blockIdx.x;
    const int t = threadIdx.x;
    const int w = t >> 6;
    float* p = sc + (long)r * 1024;
    f32x4 v = reinterpret_cast<const f32x4*>(p)[t];
    float m = fmaxf(fmaxf(v.x, v.y), fmaxf(v.z, v.w));
    #pragma unroll
    for (int d = 32; d >= 1; d >>= 1) m = fmaxf(m, __shfl_xor(m, d));
    if ((t & 63) == 0) red[w] = m;
    __syncthreads();
    m = fmaxf(fmaxf(red[0], red[1]), fmaxf(red[2], red[3]));
    f32x4 e;
    e.x = __expf(v.x - m); e.y = __expf(v.y - m);
    e.z = __expf(v.z - m); e.w = __expf(v.w - m);
    float s = e.x + e.y + e.z + e.w;
    #pragma unroll
    for (int d = 32; d >= 1; d >>= 1) s += __shfl_xor(s, d);
    if ((t & 63) == 0) red[4 + w] = s;
    __syncthreads();
    s = red[4] + red[5] + red[6] + red[7];
    const float inv = 1.0f / s;
    ushort4 o;
    o.x = f2b(e.x * inv); o.y = f2b(e.y * inv);
    o.z = f2b(e.z * inv); o.w = f2b(e.w * inv);
    reinterpret_cast<ushort4*>(reinterpret_cast<u16*>(sc) + (long)r * 2048)[t] = o;
}

// ---------------- LayerNorm over D=512, one wave per row ----------------
__global__ __launch_bounds__(256) void k_layernorm(const float* __restrict__ in,
                                                   const float* __restrict__ g,
                                                   const float* __restrict__ be,
                                                   float* __restrict__ of,
                                                   u16* __restrict__ ob) {
    const int w = threadIdx.x >> 6;
    const int l = threadIdx.x & 63;
    const long row = (long)blockIdx.x * 4 + w;
    const float* p = in + row * 512;
    f32x4 v0 = *reinterpret_cast<const f32x4*>(p + l * 4);
    f32x4 v1 = *reinterpret_cast<const f32x4*>(p + 256 + l * 4);
    float s = v0.x + v0.y + v0.z + v0.w + v1.x + v1.y + v1.z + v1.w;
    float q = v0.x * v0.x + v0.y * v0.y + v0.z * v0.z + v0.w * v0.w
            + v1.x * v1.x + v1.y * v1.y + v1.z * v1.z + v1.w * v1.w;
    #pragma unroll
    for (int d = 32; d >= 1; d >>= 1) { s += __shfl_xor(s, d); q += __shfl_xor(q, d); }
    const float mean = s * (1.0f / 512.0f);
    const float var = q * (1.0f / 512.0f) - mean * mean;
    const float inv = rsqrtf(var + 1e-5f);
    f32x4 ga = *reinterpret_cast<const f32x4*>(g + l * 4);
    f32x4 gb = *reinterpret_cast<const f32x4*>(g + 256 + l * 4);
    f32x4 ba = *reinterpret_cast<const f32x4*>(be + l * 4);
    f32x4 bb = *reinterpret_cast<const f32x4*>(be + 256 + l * 4);
    f32x4 o0 = (v0 - mean) * inv * ga + ba;
    f32x4 o1 = (v1 - mean) * inv * gb + bb;
    *reinterpret_cast<f32x4*>(of + row * 512 + l * 4) = o0;
    *reinterpret_cast<f32x4*>(of + row * 512 + 256 + l * 4) = o1;
    if (ob) {
        ushort4 p0, p1;
        p0.x = f2b(o0.x); p0.y = f2b(o0.y); p0.z = f2b(o0.z); p0.w = f2b(o0.w);
        p1.x = f2b(o1.x); p1.y = f2b(o1.y); p1.z = f2b(o1.z); p1.w = f2b(o1.w);
        *reinterpret_cast<ushort4*>(ob + row * 512 + l * 4) = p0;
        *reinterpret_cast<ushort4*>(ob + row * 512 + 256 + l * 4) = p1;
    }
}

extern "C" void kernel_launch(void* const* d_in, const int* in_sizes, int n_in,
                              void* d_out, int out_size, void* d_ws, size_t ws_size,
                              hipStream_t stream) {
    const float* x   = (const float*)d_in[0];
    const float* Wq  = (const float*)d_in[1];
    const float* bq  = (const float*)d_in[2];
    const float* Wk  = (const float*)d_in[3];
    const float* bk  = (const float*)d_in[4];
    const float* Wv  = (const float*)d_in[5];
    const float* bv  = (const float*)d_in[6];
    const float* Wo  = (const float*)d_in[7];
    const float* bo  = (const float*)d_in[8];
    const float* g0  = (const float*)d_in[9];
    const float* be0 = (const float*)d_in[10];
    const float* W1  = (const float*)d_in[11];
    const float* b1  = (const float*)d_in[12];
    const float* W2  = (const float*)d_in[13];
    const float* b2  = (const float*)d_in[14];
    const float* g1  = (const float*)d_in[15];
    const float* be1 = (const float*)d_in[16];
    float* out = (float*)d_out;

    // ---- workspace layout, peak 194.0 MB ----
    char* ws = (char*)d_ws;
    u16*   xb     = (u16*)(ws + 0);            // [8192,512] bf16
    u16*   Wqb    = (u16*)(ws + 8388608);      // [Wq;Wk] contiguous [8192,512] bf16
    u16*   Wkb    = (u16*)(ws + 12582912);
    u16*   Wvb    = (u16*)(ws + 16777216);
    u16*   Wob    = (u16*)(ws + 20971520);
    u16*   W1b    = (u16*)(ws + 25165824);
    u16*   W2b    = (u16*)(ws + 25690112);
    // R1+R2 [26214400 .. 160432128): fused QK output [8192,8192] bf16 (Q cols 0..4095, K 4096..8191)
    u16*   QKb    = (u16*)(ws + 26214400);
    u16*   VTb    = QKb;                       // [8][4096,1024] bf16 (QK dead after scores)
    float* hsum   = (float*)(ws + 26214400);   // [8192,512] f32 (VT dead after PV)
    float* hf     = (float*)(ws + 42991616);
    u16*   hb     = (u16*)(ws + 59768832);
    u16*   ff1b   = (u16*)(ws + 68157440);
    float* t2     = (float*)(ws + 76546048);
    u16*   sdpab  = (u16*)(ws + 93323264);     // [8][1024,4096] bf16
    // R3 [160432128 .. 193986560): scores f32, attn bf16 in-place (ld 2048)
    float* scores = (float*)(ws + 160432128);
    u16*   attnb  = (u16*)scores;
    float* bqk    = (float*)(ws + 160432128);  // [bq;bk] 32KB, dead once scores GEMM writes

    hipMemcpyAsync(bqk,        bq, 4096 * 4, hipMemcpyDeviceToDevice, stream);
    hipMemcpyAsync(bqk + 4096, bk, 4096 * 4, hipMemcpyDeviceToDevice, stream);

    k_convert<<<4096, 256, 0, stream>>>(x,  xb,  1048576);
    k_convert<<<2048, 256, 0, stream>>>(Wq, Wqb, 524288);
    k_convert<<<2048, 256, 0, stream>>>(Wk, Wkb, 524288);
    k_convert<<<2048, 256, 0, stream>>>(Wv, Wvb, 524288);
    k_convert<<<2048, 256, 0, stream>>>(Wo, Wob, 524288);
    k_convert<<<256,  256, 0, stream>>>(W1, W1b, 65536);
    k_convert<<<256,  256, 0, stream>>>(W2, W2b, 65536);

    const float scl = 0.044194173824159216f; // 1/sqrt(512)
    const size_t LDS_A8 = 131072;  // AM=8: 256x256 tile
    const size_t LDS_A4 = 98304;   // AM=4: 128x256 tile

    // [Q|K] = x·[Wq;Wk]^T + [bq;bk]   [8192,8192]   grid 1024 blocks
    gemm_nt256<8,1,0><<<dim3(32,32,1), 512, LDS_A8, stream>>>(xb,0, Wqb,0, bqk, QKb,0, 512,512,8192, 512, 1.0f);
    // scores[b] = (Q[b]·K[b]^T)/sqrt(512)  f32 [8][1024,1024]   BM=128 -> grid (4,8,8)=256 blocks (was 128)
    gemm_nt256<4,0,1><<<dim3(4,8,8), 512, LDS_A4, stream>>>(QKb,8388608, QKb+4096,8388608, nullptr, scores,1048576, 8192,8192,1024, 4096, scl);
    // attn = softmax(scores) -> bf16 in-place (row stride 2048)
    k_softmax<<<8192, 256, 0, stream>>>(scores);
    // V^T[b] = Wv·x[b]^T + bv(row)   [8][4096,1024]   grid 512 blocks
    gemm_nt256<8,2,0><<<dim3(4,16,8), 512, LDS_A8, stream>>>(Wvb,0, xb,524288, bv, VTb,4194304, 512,512,1024, 512, 1.0f);
    // sdpa[b] = attn[b]·(V^T[b])^T   [8][1024,4096]   grid 512 blocks
    gemm_nt256<8,0,0><<<dim3(16,4,8), 512, LDS_A8, stream>>>(attnb,2097152, VTb,4194304, nullptr, sdpab,4194304, 2048,1024,4096, 1024, 1.0f);
    // hsum = sdpa·Wo^T + bo + x   f32 [8192,512]   (128^2 kernel, 256 blocks)
    gemm_nt<1,0,1,1><<<dim3(4,64,1), 256, 0, stream>>>(sdpab,0, Wob,0, bo, x,0, hsum,0, 4096,4096,512, 4096, 1.0f);
    // h = LN(hsum) -> f32 + bf16
    k_layernorm<<<2048, 256, 0, stream>>>(hsum, g0, be0, hf, hb);
    // ff1 = relu(h·W1^T + b1) bf16
    gemm_nt<1,1,0,0><<<dim3(4,64,1), 256, 0, stream>>>(hb,0, W1b,0, b1, nullptr,0, ff1b,0, 512,512,512, 512, 1.0f);
    // t2 = ff1·W2^T + b2 + h  f32
    gemm_nt<1,0,1,1><<<dim3(4,64,1), 256, 0, stream>>>(ff1b,0, W2b,0, b2, hf,0, t2,0, 512,512,512, 512, 1.0f);
    // out = LN(t2)
    k_layernorm<<<2048, 256, 0, stream>>>(t2, g1, be1, out, nullptr);
}

// Round 8
// 633.809 us; speedup vs baseline: 1.3616x; 1.0113x over previous
//
#include <hip/hip_runtime.h>

typedef unsigned short u16;
typedef unsigned int u32;
typedef float f32x4 __attribute__((ext_vector_type(4)));
typedef __bf16 bf16x8 __attribute__((ext_vector_type(8)));

__device__ __forceinline__ u16 f2b(float f) {
    u32 b = __builtin_bit_cast(u32, f);
    b = b + 0x7FFFu + ((b >> 16) & 1u);
    return (u16)(b >> 16);
}

// ---------------- fp32 -> bf16 convert (4 elems/thread) ----------------
__global__ __launch_bounds__(256) void k_convert(const float* __restrict__ in,
                                                 u16* __restrict__ out, int n4) {
    int i = blockIdx.x * 256 + threadIdx.x;
    if (i >= n4) return;
    f32x4 v = reinterpret_cast<const f32x4*>(in)[i];
    ushort4 o;
    o.x = f2b(v.x); o.y = f2b(v.y); o.z = f2b(v.z); o.w = f2b(v.w);
    reinterpret_cast<ushort4*>(out)[i] = o;
}

// ------ fused weight convert: Wq,Wk,Wv,Wo (524288 n4 each) + W1,W2 (65536 n4) -> contiguous dst ----
__global__ __launch_bounds__(256) void k_convert_w(const float* __restrict__ wq, const float* __restrict__ wk,
                                                   const float* __restrict__ wv, const float* __restrict__ wo,
                                                   const float* __restrict__ w1, const float* __restrict__ w2,
                                                   u16* __restrict__ dst) {
    const int b = blockIdx.x;
    const float* src;
    long dof;
    int li;
    if (b < 8192) {             // 4 big weights, 2048 blocks each
        const int wsel = b >> 11;
        li = (b & 2047) * 256 + threadIdx.x;
        src = wsel == 0 ? wq : wsel == 1 ? wk : wsel == 2 ? wv : wo;
        dof = (long)wsel * 2097152 + (long)li * 4;
    } else {
        const int wsel = (b - 8192) >> 8;
        li = ((b - 8192) & 255) * 256 + threadIdx.x;
        src = wsel == 0 ? w1 : w2;
        dof = 8388608 + (long)wsel * 262144 + (long)li * 4;
    }
    f32x4 v = reinterpret_cast<const f32x4*>(src)[li];
    ushort4 o;
    o.x = f2b(v.x); o.y = f2b(v.y); o.z = f2b(v.z); o.w = f2b(v.w);
    *reinterpret_cast<ushort4*>(dst + dof) = o;
}

// ============ 128^2 NT bf16 GEMM — round-3 proven structure (single buffer) + XCD swizzle ======
template<int BIAS /*0 none,1 col,2 row*/, int ACT, int OUTF32, int RES>
__global__ __launch_bounds__(256, 2) void gemm_nt(
    const u16* __restrict__ A, long sA,
    const u16* __restrict__ B, long sB,
    const float* __restrict__ bias,
    const float* __restrict__ res, long sRes,
    void* __restrict__ Cv, long sC,
    int ldA, int ldB, int ldC, int K, float scale)
{
    __shared__ u16 Al[8192];
    __shared__ u16 Bl[8192];
    const int tid = threadIdx.x;

    const int nx = gridDim.x, ny = gridDim.y;
    const int nwg = nx * ny * (int)gridDim.z;
    int orig = blockIdx.x + nx * (blockIdx.y + ny * blockIdx.z);
    int wg = ((nwg & 7) == 0) ? ((orig & 7) * (nwg >> 3) + (orig >> 3)) : orig;
    const int bx = wg % nx;
    const int tmp = wg / nx;
    const int by = tmp % ny;
    const int bz = tmp / ny;

    const int m0 = by * 128;
    const int n0 = bx * 128;
    A += (long)bz * sA;
    B += (long)bz * sB;
    const int l = tid & 63;
    const int w = tid >> 6;
    const int wr = w >> 1, wc = w & 1;

    const int fr = l & 15;
    const int fk = (l >> 4) * 8;
    const u16* gA = A + (long)(m0 + w * 32 + fr) * ldA + fk;
    const u16* gB = B + (long)(n0 + w * 32 + fr) * ldB + fk;
    u16* lA = &Al[w * 2048];
    u16* lB = &Bl[w * 2048];

    f32x4 acc[4][4] = {};

    for (int k0 = 0; k0 < K; k0 += 64) {
        __syncthreads();
        #pragma unroll
        for (int q = 0; q < 4; q++) {
            const long ka = k0 + (q & 1) * 32 + (long)(q >> 1) * 16 * ldA;
            const long kb = k0 + (q & 1) * 32 + (long)(q >> 1) * 16 * ldB;
            __builtin_amdgcn_global_load_lds(
                (const __attribute__((address_space(1))) u32*)(gA + ka),
                (__attribute__((address_space(3))) u32*)(lA + q * 512), 16, 0, 0);
            __builtin_amdgcn_global_load_lds(
                (const __attribute__((address_space(1))) u32*)(gB + kb),
                (__attribute__((address_space(3))) u32*)(lB + q * 512), 16, 0, 0);
        }
        __syncthreads();
        #pragma unroll
        for (int ks = 0; ks < 2; ks++) {
            bf16x8 af[4], bfr[4];
            #pragma unroll
            for (int t = 0; t < 4; t++) {
                af[t]  = *reinterpret_cast<const bf16x8*>(&Al[((wr * 4 + t) * 2 + ks) * 512 + l * 8]);
                bfr[t] = *reinterpret_cast<const bf16x8*>(&Bl[((wc * 4 + t) * 2 + ks) * 512 + l * 8]);
            }
            #pragma unroll
            for (int mt = 0; mt < 4; mt++)
                #pragma unroll
                for (int nt = 0; nt < 4; nt++)
                    acc[mt][nt] = __builtin_amdgcn_mfma_f32_16x16x32_bf16(af[mt], bfr[nt], acc[mt][nt], 0, 0, 0);
        }
    }

    const int lr = (l >> 4) * 4;
    const int lc = l & 15;
    #pragma unroll
    for (int mt = 0; mt < 4; mt++) {
        #pragma unroll
        for (int i = 0; i < 4; i++) {
            const int row = m0 + wr * 64 + mt * 16 + lr + i;
            #pragma unroll
            for (int nt = 0; nt < 4; nt++) {
                const int col = n0 + wc * 64 + nt * 16 + lc;
                float v = acc[mt][nt][i] * scale;
                if (BIAS == 1) v += bias[col];
                if (BIAS == 2) v += bias[row];
                if (ACT) v = fmaxf(v, 0.0f);
                if (RES) v += res[(long)bz * sRes + (long)row * ldC + col];
                const long ci = (long)bz * sC + (long)row * ldC + col;
                if (OUTF32) ((float*)Cv)[ci] = v;
                else        ((u16*)Cv)[ci] = f2b(v);
            }
        }
    }
}

// ============ big-tile NT bf16 GEMM — T3/T4 schedule, BM = 32*AM x BN = 256 ============
// 512 threads (8 waves 2M x 4N), BK=64. Per-wave out (AM*16) x 64 -> acc[AM][4] f32x4.
// ksc-OUTER phase order (r6): B fragments (bfv) loaded once per ksc, reused across both
// m-halves -> B LDS reads halved (AM=4: 24->16 reads/K-step vs 32 MFMA; AM=8: 32->24 vs 64).
// Sync structure IDENTICAL to verified r5 kernel: per K-tile t { vmcnt(0) [tile-t loads,
// issued one full iter ago]; s_barrier; sched_barrier; 4 sub-phases each issuing 1 STAGE }.
template<int AM, int BIAS /*0,1 col,2 row*/, int OUTF32>
__global__ __launch_bounds__(512, 2) void gemm_nt256(
    const u16* __restrict__ A, long sA,
    const u16* __restrict__ B, long sB,
    const float* __restrict__ bias,
    void* __restrict__ Cv, long sC,
    int ldA, int ldB, int ldC, int K, float scale)
{
    extern __shared__ u16 lds[];
    constexpr int AS = AM * 2048;   // per-buffer A size in u16
    const int tid = threadIdx.x;

    const int nx = gridDim.x, ny = gridDim.y;
    const int nwg = nx * ny * (int)gridDim.z;
    int orig = blockIdx.x + nx * (blockIdx.y + ny * blockIdx.z);
    int wg = ((nwg & 7) == 0) ? ((orig & 7) * (nwg >> 3) + (orig >> 3)) : orig;
    const int bx = wg % nx;
    const int tmp = wg / nx;
    const int by = tmp % ny;
    const int bz = tmp / ny;

    const int m0 = by * (AM * 32);
    const int n0 = bx * 256;
    A += (long)bz * sA;
    B += (long)bz * sB;
    const int l = tid & 63;
    const int w = tid >> 6;          // 0..7
    const int wr = w >> 2, wc = w & 3;

    const int fr = l & 15;
    const int fk = (l >> 4) * 8;
    const int ksS = w & 1;
    const int mtS = w >> 1;
    const u16* gA = A + (long)(m0 + mtS * 16 + fr) * ldA + ksS * 32 + fk;
    const u16* gB = B + (long)(n0 + mtS * 16 + fr) * ldB + ksS * 32 + fk;

    f32x4 acc[AM][4] = {};
    const int nt = K >> 6;

#define STAGE2(buf, k1, p)                                                                   \
    {                                                                                        \
        if ((p) < AM / 2)                                                                    \
            __builtin_amdgcn_global_load_lds(                                                \
                (const __attribute__((address_space(1))) u32*)(gA + (long)(p) * 64 * ldA + (k1)),\
                (__attribute__((address_space(3))) u32*)(lds + (buf) * AS + ((p) * 8 + w) * 512), 16, 0, 0); \
        __builtin_amdgcn_global_load_lds(                                                    \
            (const __attribute__((address_space(1))) u32*)(gB + (long)(p) * 64 * ldB + (k1)),\
            (__attribute__((address_space(3))) u32*)(lds + 2 * AS + (buf) * 16384 + ((p) * 8 + w) * 512), 16, 0, 0); \
    }

#define LOADB(buf, ksc)                                                                      \
    _Pragma("unroll")                                                                        \
    for (int t4 = 0; t4 < 4; t4++)                                                           \
        bfv[t4] = *reinterpret_cast<const bf16x8*>(                                          \
            lds + 2 * AS + (buf) * 16384 + ((wc * 4 + t4) * 2 + (ksc)) * 512 + l * 8);

#define LOADA(buf, mh, ksc)                                                                  \
    _Pragma("unroll")                                                                        \
    for (int t4 = 0; t4 < AM / 2; t4++)                                                      \
        af[t4] = *reinterpret_cast<const bf16x8*>(                                           \
            lds + (buf) * AS + ((wr * AM + (mh) * (AM / 2) + t4) * 2 + (ksc)) * 512 + l * 8);

#define DOMFMA(mh)                                                                           \
    __builtin_amdgcn_s_setprio(1);                                                           \
    _Pragma("unroll")                                                                        \
    for (int mi = 0; mi < AM / 2; mi++)                                                      \
        _Pragma("unroll")                                                                    \
        for (int ni = 0; ni < 4; ni++)                                                       \
            acc[(mh) * (AM / 2) + mi][ni] = __builtin_amdgcn_mfma_f32_16x16x32_bf16(         \
                af[mi], bfv[ni], acc[(mh) * (AM / 2) + mi][ni], 0, 0, 0);                    \
    __builtin_amdgcn_s_setprio(0);

    STAGE2(0, 0, 0); STAGE2(0, 0, 1); STAGE2(0, 0, 2); STAGE2(0, 0, 3);

    for (int t = 0; t < nt; ++t) {
        const int buf = t & 1;
        asm volatile("s_waitcnt vmcnt(0)" ::: "memory");
        __builtin_amdgcn_s_barrier();
        __builtin_amdgcn_sched_barrier(0);
        const bool st = (t + 1) < nt;
        const int k1 = (t + 1) << 6;
        bf16x8 bfv[4], af[AM / 2];
        // ksc = 0
        LOADB(buf, 0); LOADA(buf, 0, 0);
        if (st) STAGE2(buf ^ 1, k1, 0);
        DOMFMA(0);
        LOADA(buf, 1, 0);
        if (st) STAGE2(buf ^ 1, k1, 1);
        DOMFMA(1);
        // ksc = 1
        LOADB(buf, 1); LOADA(buf, 0, 1);
        if (st) STAGE2(buf ^ 1, k1, 2);
        DOMFMA(0);
        LOADA(buf, 1, 1);
        if (st) STAGE2(buf ^ 1, k1, 3);
        DOMFMA(1);
    }
#undef STAGE2
#undef LOADB
#undef LOADA
#undef DOMFMA

    const int lr = (l >> 4) * 4;
    const int lc = l & 15;
    #pragma unroll
    for (int mf = 0; mf < AM; mf++) {
        #pragma unroll
        for (int i = 0; i < 4; i++) {
            const int row = m0 + wr * (AM * 16) + mf * 16 + lr + i;
            #pragma unroll
            for (int ni = 0; ni < 4; ni++) {
                const int col = n0 + wc * 64 + ni * 16 + lc;
                float v = acc[mf][ni][i] * scale;
                if (BIAS == 1) v += bias[col];
                if (BIAS == 2) v += bias[row];
                const long ci = (long)bz * sC + (long)row * ldC + col;
                if (OUTF32) ((float*)Cv)[ci] = v;
                else        ((u16*)Cv)[ci] = f2b(v);
            }
        }
    }
}

// ------- row softmax: 1024 f32 in -> 1024 bf16 written IN-PLACE (row stride 2048 u16) -------
__global__ __launch_bounds__(256) void k_softmax(float* __restrict__ sc) {
    __shared__ float red[8];
    const int r = blockIdx.x;
    const int t = threadIdx.x;
    const int w = t >> 6;
    float* p = sc + (long)r * 1024;
    f32x4 v = reinterpret_cast<const f32x4*>(p)[t];
    float m = fmaxf(fmaxf(v.x, v.y), fmaxf(v.z, v.w));
    #pragma unroll
    for (int d = 32; d >= 1; d >>= 1) m = fmaxf(m, __shfl_xor(m, d));
    if ((t & 63) == 0) red[w] = m;
    __syncthreads();
    m = fmaxf(fmaxf(red[0], red[1]), fmaxf(red[2], red[3]));
    f32x4 e;
    e.x = __expf(v.x - m); e.y = __expf(v.y - m);
    e.z = __expf(v.z - m); e.w = __expf(v.w - m);
    float s = e.x + e.y + e.z + e.w;
    #pragma unroll
    for (int d = 32; d >= 1; d >>= 1) s += __shfl_xor(s, d);
    if ((t & 63) == 0) red[4 + w] = s;
    __syncthreads();
    s = red[4] + red[5] + red[6] + red[7];
    const float inv = 1.0f / s;
    ushort4 o;
    o.x = f2b(e.x * inv); o.y = f2b(e.y * inv);
    o.z = f2b(e.z * inv); o.w = f2b(e.w * inv);
    reinterpret_cast<ushort4*>(reinterpret_cast<u16*>(sc) + (long)r * 2048)[t] = o;
}

// ---------------- LayerNorm over D=512, one wave per row ----------------
__global__ __launch_bounds__(256) void k_layernorm(const float* __restrict__ in,
                                                   const float* __restrict__ g,
                                                   const float* __restrict__ be,
                                                   float* __restrict__ of,
                                                   u16* __restrict__ ob) {
    const int w = threadIdx.x >> 6;
    const int l = threadIdx.x & 63;
    const long row = (long)blockIdx.x * 4 + w;
    const float* p = in + row * 512;
    f32x4 v0 = *reinterpret_cast<const f32x4*>(p + l * 4);
    f32x4 v1 = *reinterpret_cast<const f32x4*>(p + 256 + l * 4);
    float s = v0.x + v0.y + v0.z + v0.w + v1.x + v1.y + v1.z + v1.w;
    float q = v0.x * v0.x + v0.y * v0.y + v0.z * v0.z + v0.w * v0.w
            + v1.x * v1.x + v1.y * v1.y + v1.z * v1.z + v1.w * v1.w;
    #pragma unroll
    for (int d = 32; d >= 1; d >>= 1) { s += __shfl_xor(s, d); q += __shfl_xor(q, d); }
    const float mean = s * (1.0f / 512.0f);
    const float var = q * (1.0f / 512.0f) - mean * mean;
    const float inv = rsqrtf(var + 1e-5f);
    f32x4 ga = *reinterpret_cast<const f32x4*>(g + l * 4);
    f32x4 gb = *reinterpret_cast<const f32x4*>(g + 256 + l * 4);
    f32x4 ba = *reinterpret_cast<const f32x4*>(be + l * 4);
    f32x4 bb = *reinterpret_cast<const f32x4*>(be + 256 + l * 4);
    f32x4 o0 = (v0 - mean) * inv * ga + ba;
    f32x4 o1 = (v1 - mean) * inv * gb + bb;
    *reinterpret_cast<f32x4*>(of + row * 512 + l * 4) = o0;
    *reinterpret_cast<f32x4*>(of + row * 512 + 256 + l * 4) = o1;
    if (ob) {
        ushort4 p0, p1;
        p0.x = f2b(o0.x); p0.y = f2b(o0.y); p0.z = f2b(o0.z); p0.w = f2b(o0.w);
        p1.x = f2b(o1.x); p1.y = f2b(o1.y); p1.z = f2b(o1.z); p1.w = f2b(o1.w);
        *reinterpret_cast<ushort4*>(ob + row * 512 + l * 4) = p0;
        *reinterpret_cast<ushort4*>(ob + row * 512 + 256 + l * 4) = p1;
    }
}

extern "C" void kernel_launch(void* const* d_in, const int* in_sizes, int n_in,
                              void* d_out, int out_size, void* d_ws, size_t ws_size,
                              hipStream_t stream) {
    const float* x   = (const float*)d_in[0];
    const float* Wq  = (const float*)d_in[1];
    const float* bq  = (const float*)d_in[2];
    const float* Wk  = (const float*)d_in[3];
    const float* bk  = (const float*)d_in[4];
    const float* Wv  = (const float*)d_in[5];
    const float* bv  = (const float*)d_in[6];
    const float* Wo  = (const float*)d_in[7];
    const float* bo  = (const float*)d_in[8];
    const float* g0  = (const float*)d_in[9];
    const float* be0 = (const float*)d_in[10];
    const float* W1  = (const float*)d_in[11];
    const float* b1  = (const float*)d_in[12];
    const float* W2  = (const float*)d_in[13];
    const float* b2  = (const float*)d_in[14];
    const float* g1  = (const float*)d_in[15];
    const float* be1 = (const float*)d_in[16];
    float* out = (float*)d_out;

    // ---- workspace layout, peak 194.0 MB ----
    char* ws = (char*)d_ws;
    u16*   xb     = (u16*)(ws + 0);            // [8192,512] bf16
    u16*   Wqb    = (u16*)(ws + 8388608);      // [Wq;Wk] contiguous [8192,512] bf16
    u16*   Wvb    = (u16*)(ws + 16777216);
    u16*   Wob    = (u16*)(ws + 20971520);
    u16*   W1b    = (u16*)(ws + 25165824);
    u16*   W2b    = (u16*)(ws + 25690112);
    // R1+R2 [26214400 .. 160432128): fused QK output [8192,8192] bf16 (Q cols 0..4095, K 4096..8191)
    u16*   QKb    = (u16*)(ws + 26214400);
    u16*   VTb    = QKb;                       // [8][4096,1024] bf16 (QK dead after scores)
    float* hsum   = (float*)(ws + 26214400);   // [8192,512] f32 (VT dead after PV)
    float* hf     = (float*)(ws + 42991616);
    u16*   hb     = (u16*)(ws + 59768832);
    u16*   ff1b   = (u16*)(ws + 68157440);
    float* t2     = (float*)(ws + 76546048);
    u16*   sdpab  = (u16*)(ws + 93323264);     // [8][1024,4096] bf16
    // R3 [160432128 .. 193986560): scores f32, attn bf16 in-place (ld 2048)
    float* scores = (float*)(ws + 160432128);
    u16*   attnb  = (u16*)scores;
    float* bqk    = (float*)(ws + 160432128);  // [bq;bk] 32KB, dead once scores GEMM writes

    hipMemcpyAsync(bqk,        bq, 4096 * 4, hipMemcpyDeviceToDevice, stream);
    hipMemcpyAsync(bqk + 4096, bk, 4096 * 4, hipMemcpyDeviceToDevice, stream);

    k_convert<<<4096, 256, 0, stream>>>(x, xb, 1048576);
    k_convert_w<<<8704, 256, 0, stream>>>(Wq, Wk, Wv, Wo, W1, W2, Wqb);

    const float scl = 0.044194173824159216f; // 1/sqrt(512)
    const size_t LDS_A8 = 131072;  // AM=8: 256x256 tile
    const size_t LDS_A4 = 98304;   // AM=4: 128x256 tile

    // [Q|K] = x·[Wq;Wk]^T + [bq;bk]   [8192,8192]   grid 1024 blocks
    gemm_nt256<8,1,0><<<dim3(32,32,1), 512, LDS_A8, stream>>>(xb,0, Wqb,0, bqk, QKb,0, 512,512,8192, 512, 1.0f);
    // scores[b] = (Q[b]·K[b]^T)/sqrt(512)  f32 [8][1024,1024]   BM=128 -> grid (4,8,8)=256 blocks
    gemm_nt256<4,0,1><<<dim3(4,8,8), 512, LDS_A4, stream>>>(QKb,8388608, QKb+4096,8388608, nullptr, scores,1048576, 8192,8192,1024, 4096, scl);
    // attn = softmax(scores) -> bf16 in-place (row stride 2048)
    k_softmax<<<8192, 256, 0, stream>>>(scores);
    // V^T[b] = Wv·x[b]^T + bv(row)   [8][4096,1024]   grid 512 blocks
    gemm_nt256<8,2,0><<<dim3(4,16,8), 512, LDS_A8, stream>>>(Wvb,0, xb,524288, bv, VTb,4194304, 512,512,1024, 512, 1.0f);
    // sdpa[b] = attn[b]·(V^T[b])^T   [8][1024,4096]   grid 512 blocks
    gemm_nt256<8,0,0><<<dim3(16,4,8), 512, LDS_A8, stream>>>(attnb,2097152, VTb,4194304, nullptr, sdpab,4194304, 2048,1024,4096, 1024, 1.0f);
    // hsum = sdpa·Wo^T + bo + x   f32 [8192,512]   (128^2 kernel, 256 blocks)
    gemm_nt<1,0,1,1><<<dim3(4,64,1), 256, 0, stream>>>(sdpab,0, Wob,0, bo, x,0, hsum,0, 4096,4096,512, 4096, 1.0f);
    // h = LN(hsum) -> f32 + bf16
    k_layernorm<<<2048, 256, 0, stream>>>(hsum, g0, be0, hf, hb);
    // ff1 = relu(h·W1^T + b1) bf16
    gemm_nt<1,1,0,0><<<dim3(4,64,1), 256, 0, stream>>>(hb,0, W1b,0, b1, nullptr,0, ff1b,0, 512,512,512, 512, 1.0f);
    // t2 = ff1·W2^T + b2 + h  f32
    gemm_nt<1,0,1,1><<<dim3(4,64,1), 256, 0, stream>>>(ff1b,0, W2b,0, b2, hf,0, t2,0, 512,512,512, 512, 1.0f);
    // out = LN(t2)
    k_layernorm<<<2048, 256, 0, stream>>>(t2, g1, be1, out, nullptr);
}

// Round 10
// 591.252 us; speedup vs baseline: 1.4596x; 1.0720x over previous
//
#include <hip/hip_runtime.h>

typedef unsigned short u16;
typedef unsigned int u32;
typedef float f32x4 __attribute__((ext_vector_type(4)));
typedef __bf16 bf16x8 __attribute__((ext_vector_type(8)));

__device__ __forceinline__ u16 f2b(float f) {
    u32 b = __builtin_bit_cast(u32, f);
    b = b + 0x7FFFu + ((b >> 16) & 1u);
    return (u16)(b >> 16);
}

// ---------------- fp32 -> bf16 convert (4 elems/thread) ----------------
__global__ __launch_bounds__(256) void k_convert(const float* __restrict__ in,
                                                 u16* __restrict__ out, int n4) {
    int i = blockIdx.x * 256 + threadIdx.x;
    if (i >= n4) return;
    f32x4 v = reinterpret_cast<const f32x4*>(in)[i];
    ushort4 o;
    o.x = f2b(v.x); o.y = f2b(v.y); o.z = f2b(v.z); o.w = f2b(v.w);
    reinterpret_cast<ushort4*>(out)[i] = o;
}

// ------ fused weight convert: Wq,Wk,Wv,Wo + W1,W2 -> contiguous dst ----
__global__ __launch_bounds__(256) void k_convert_w(const float* __restrict__ wq, const float* __restrict__ wk,
                                                   const float* __restrict__ wv, const float* __restrict__ wo,
                                                   const float* __restrict__ w1, const float* __restrict__ w2,
                                                   u16* __restrict__ dst) {
    const int b = blockIdx.x;
    const float* src;
    long dof;
    int li;
    if (b < 8192) {
        const int wsel = b >> 11;
        li = (b & 2047) * 256 + threadIdx.x;
        src = wsel == 0 ? wq : wsel == 1 ? wk : wsel == 2 ? wv : wo;
        dof = (long)wsel * 2097152 + (long)li * 4;
    } else {
        const int wsel = (b - 8192) >> 8;
        li = ((b - 8192) & 255) * 256 + threadIdx.x;
        src = wsel == 0 ? w1 : w2;
        dof = 8388608 + (long)wsel * 262144 + (long)li * 4;
    }
    f32x4 v = reinterpret_cast<const f32x4*>(src)[li];
    ushort4 o;
    o.x = f2b(v.x); o.y = f2b(v.y); o.z = f2b(v.z); o.w = f2b(v.w);
    *reinterpret_cast<ushort4*>(dst + dof) = o;
}

// ============ 128^2 NT bf16 GEMM — round-3 proven structure (single buffer) + XCD swizzle ======
template<int BIAS /*0 none,1 col,2 row*/, int ACT, int OUTF32, int RES>
__global__ __launch_bounds__(256, 2) void gemm_nt(
    const u16* __restrict__ A, long sA,
    const u16* __restrict__ B, long sB,
    const float* __restrict__ bias,
    const float* __restrict__ res, long sRes,
    void* __restrict__ Cv, long sC,
    int ldA, int ldB, int ldC, int K, float scale)
{
    __shared__ u16 Al[8192];
    __shared__ u16 Bl[8192];
    const int tid = threadIdx.x;

    const int nx = gridDim.x, ny = gridDim.y;
    const int nwg = nx * ny * (int)gridDim.z;
    int orig = blockIdx.x + nx * (blockIdx.y + ny * blockIdx.z);
    int wg = ((nwg & 7) == 0) ? ((orig & 7) * (nwg >> 3) + (orig >> 3)) : orig;
    const int bx = wg % nx;
    const int tmp = wg / nx;
    const int by = tmp % ny;
    const int bz = tmp / ny;

    const int m0 = by * 128;
    const int n0 = bx * 128;
    A += (long)bz * sA;
    B += (long)bz * sB;
    const int l = tid & 63;
    const int w = tid >> 6;
    const int wr = w >> 1, wc = w & 1;

    const int fr = l & 15;
    const int fk = (l >> 4) * 8;
    const u16* gA = A + (long)(m0 + w * 32 + fr) * ldA + fk;
    const u16* gB = B + (long)(n0 + w * 32 + fr) * ldB + fk;
    u16* lA = &Al[w * 2048];
    u16* lB = &Bl[w * 2048];

    f32x4 acc[4][4] = {};

    for (int k0 = 0; k0 < K; k0 += 64) {
        __syncthreads();
        #pragma unroll
        for (int q = 0; q < 4; q++) {
            const long ka = k0 + (q & 1) * 32 + (long)(q >> 1) * 16 * ldA;
            const long kb = k0 + (q & 1) * 32 + (long)(q >> 1) * 16 * ldB;
            __builtin_amdgcn_global_load_lds(
                (const __attribute__((address_space(1))) u32*)(gA + ka),
                (__attribute__((address_space(3))) u32*)(lA + q * 512), 16, 0, 0);
            __builtin_amdgcn_global_load_lds(
                (const __attribute__((address_space(1))) u32*)(gB + kb),
                (__attribute__((address_space(3))) u32*)(lB + q * 512), 16, 0, 0);
        }
        __syncthreads();
        #pragma unroll
        for (int ks = 0; ks < 2; ks++) {
            bf16x8 af[4], bfr[4];
            #pragma unroll
            for (int t = 0; t < 4; t++) {
                af[t]  = *reinterpret_cast<const bf16x8*>(&Al[((wr * 4 + t) * 2 + ks) * 512 + l * 8]);
                bfr[t] = *reinterpret_cast<const bf16x8*>(&Bl[((wc * 4 + t) * 2 + ks) * 512 + l * 8]);
            }
            #pragma unroll
            for (int mt = 0; mt < 4; mt++)
                #pragma unroll
                for (int nt = 0; nt < 4; nt++)
                    acc[mt][nt] = __builtin_amdgcn_mfma_f32_16x16x32_bf16(af[mt], bfr[nt], acc[mt][nt], 0, 0, 0);
        }
    }

    const int lr = (l >> 4) * 4;
    const int lc = l & 15;
    #pragma unroll
    for (int mt = 0; mt < 4; mt++) {
        #pragma unroll
        for (int i = 0; i < 4; i++) {
            const int row = m0 + wr * 64 + mt * 16 + lr + i;
            #pragma unroll
            for (int nt = 0; nt < 4; nt++) {
                const int col = n0 + wc * 64 + nt * 16 + lc;
                float v = acc[mt][nt][i] * scale;
                if (BIAS == 1) v += bias[col];
                if (BIAS == 2) v += bias[row];
                if (ACT) v = fmaxf(v, 0.0f);
                if (RES) v += res[(long)bz * sRes + (long)row * ldC + col];
                const long ci = (long)bz * sC + (long)row * ldC + col;
                if (OUTF32) ((float*)Cv)[ci] = v;
                else        ((u16*)Cv)[ci] = f2b(v);
            }
        }
    }
}

// ============ big-tile NT bf16 GEMM — T3+T4 counted-vmcnt pipeline, TAIL-CORRECTED ============
// 512 thr (8 waves 2Mx4N), BM=32*AM, BN=256, BK=64. Tile t in buf t&1; tile t+1 staged to buf^1.
// Groups (FIFO): G0={A mh0-set, Bx2}(ks0) G1={A mh1}(AM8) G2,G3 same for ks1. AM8=[3,1,3,1], AM4=[3,0,3,0].
// Steady counts (FIFO ledger): AM8 vmcnt 5/7/5/7; AM4 3/-/3/-.
// TAIL (no staging -> lower outstanding; r9 bug was reusing steady counts): AM8 5/4/1/0; AM4 3/-/0/-.
// All VMEM issue points bracketed by sched_barrier(0) pairs -> counts exact.
template<int AM, int BIAS /*0,1 col,2 row*/, int OUTF32>
__global__ __launch_bounds__(512, 2) void gemm_nt256(
    const u16* __restrict__ A, long sA,
    const u16* __restrict__ B, long sB,
    const float* __restrict__ bias,
    void* __restrict__ Cv, long sC,
    int ldA, int ldB, int ldC, int K, float scale)
{
    extern __shared__ u16 lds[];
    constexpr int AS = AM * 2048;
    constexpr int BOFF = 2 * AS;
    const int tid = threadIdx.x;

    const int nx = gridDim.x, ny = gridDim.y;
    const int nwg = nx * ny * (int)gridDim.z;
    int orig = blockIdx.x + nx * (blockIdx.y + ny * blockIdx.z);
    int wg = ((nwg & 7) == 0) ? ((orig & 7) * (nwg >> 3) + (orig >> 3)) : orig;
    const int bx = wg % nx;
    const int tmp = wg / nx;
    const int by = tmp % ny;
    const int bz = tmp / ny;

    const int m0 = by * (AM * 32);
    const int n0 = bx * 256;
    A += (long)bz * sA;
    B += (long)bz * sB;
    const int l = tid & 63;
    const int w = tid >> 6;
    const int wr = w >> 2, wc = w & 3;
    const int fr = l & 15;
    const int fk = (l >> 4) * 8;

    const int mtA0 = (AM == 8) ? ((w & 3) + (w >> 2) * 8) : w;
    const int mtA1 = (AM == 8) ? (4 + (w & 3) + (w >> 2) * 8) : 0;

    f32x4 acc[AM][4] = {};
    const int nt = K >> 6;

#define GLD(src, dst) __builtin_amdgcn_global_load_lds(                          \
        (const __attribute__((address_space(1))) u32*)(src),                     \
        (__attribute__((address_space(3))) u32*)(dst), 16, 0, 0)
#define SA_(d, k1, mt, ksc) GLD(A + (long)(m0 + (mt) * 16 + fr) * ldA + (k1) + (ksc) * 32 + fk, \
                                lds + (d) * AS + ((mt) * 2 + (ksc)) * 512 + l * 8)
#define SB_(d, k1, mt, ksc) GLD(B + (long)(n0 + (mt) * 16 + fr) * ldB + (k1) + (ksc) * 32 + fk, \
                                lds + BOFF + (d) * 16384 + ((mt) * 2 + (ksc)) * 512 + l * 8)
#define VMW_(n) asm volatile("s_waitcnt vmcnt(" #n ")" ::: "memory")
#define VMW(n) VMW_(n)
#define LGK0()  asm volatile("s_waitcnt lgkmcnt(0)" ::: "memory")
#define SBAR() __builtin_amdgcn_s_barrier()
#define SCB() __builtin_amdgcn_sched_barrier(0)

#define LOADB(r, ksc)                                                            \
    _Pragma("unroll")                                                            \
    for (int t4 = 0; t4 < 4; t4++)                                               \
        bfv[t4] = *reinterpret_cast<const bf16x8*>(                              \
            lds + BOFF + (r) * 16384 + ((wc * 4 + t4) * 2 + (ksc)) * 512 + l * 8);
#define LOADA(r, mh, ksc)                                                        \
    _Pragma("unroll")                                                            \
    for (int t4 = 0; t4 < AM / 2; t4++)                                          \
        af[t4] = *reinterpret_cast<const bf16x8*>(                               \
            lds + (r) * AS + ((wr * AM + (mh) * (AM / 2) + t4) * 2 + (ksc)) * 512 + l * 8);
#define MF(mh)                                                                   \
    __builtin_amdgcn_s_setprio(1);                                               \
    _Pragma("unroll")                                                            \
    for (int mi = 0; mi < AM / 2; mi++)                                          \
        _Pragma("unroll")                                                        \
        for (int ni = 0; ni < 4; ni++)                                           \
            acc[(mh) * (AM / 2) + mi][ni] = __builtin_amdgcn_mfma_f32_16x16x32_bf16( \
                af[mi], bfv[ni], acc[(mh) * (AM / 2) + mi][ni], 0, 0, 0);        \
    __builtin_amdgcn_s_setprio(0);

// One K-tile iteration. ST: stage tile t+1. V*_8 / V*_4: vmcnt counts per phase for AM=8 / AM=4.
#define ITER(r, d, k1, ST, V0_8, V1_8, V2_8, V3_8, V0_4, V2_4)                   \
    {                                                                            \
        bf16x8 bfv[4], af[AM / 2];                                               \
        /* phase 0: (ks0, mh0) */                                                \
        if constexpr (AM == 8) { VMW(V0_8); } else { VMW(V0_4); }                \
        SBAR(); SCB();                                                           \
        LOADB(r, 0); LOADA(r, 0, 0);                                             \
        if (ST) { SA_(d, k1, mtA0, 0); SB_(d, k1, w, 0); SB_(d, k1, 8 + w, 0); } \
        LGK0(); SCB();                                                           \
        MF(0);                                                                   \
        /* phase 1: (ks0, mh1) */                                                \
        if constexpr (AM == 8) { VMW(V1_8); SBAR(); SCB(); }                     \
        LOADA(r, 1, 0);                                                          \
        if constexpr (AM == 8) { if (ST) SA_(d, k1, mtA1, 0); }                  \
        LGK0(); SCB();                                                           \
        MF(1);                                                                   \
        /* phase 2: (ks1, mh0) */                                                \
        if constexpr (AM == 8) { VMW(V2_8); } else { VMW(V2_4); }                \
        SBAR(); SCB();                                                           \
        LOADB(r, 1); LOADA(r, 0, 1);                                             \
        if (ST) { SA_(d, k1, mtA0, 1); SB_(d, k1, w, 1); SB_(d, k1, 8 + w, 1); } \
        LGK0(); SCB();                                                           \
        MF(0);                                                                   \
        /* phase 3: (ks1, mh1) */                                                \
        if constexpr (AM == 8) { VMW(V3_8); SBAR(); SCB(); }                     \
        LOADA(r, 1, 1);                                                          \
        if constexpr (AM == 8) { if (ST) SA_(d, k1, mtA1, 1); }                  \
        LGK0(); SCB();                                                           \
        MF(1);                                                                   \
    }

    // prologue: stage tile 0 into buf 0 (FIFO order G0,G1,G2,G3)
    {
        SA_(0, 0, mtA0, 0); SB_(0, 0, w, 0); SB_(0, 0, 8 + w, 0);
        if constexpr (AM == 8) SA_(0, 0, mtA1, 0);
        SA_(0, 0, mtA0, 1); SB_(0, 0, w, 1); SB_(0, 0, 8 + w, 1);
        if constexpr (AM == 8) SA_(0, 0, mtA1, 1);
    }

    for (int t = 0; t < nt - 1; ++t) {
        const int r = t & 1;
        const int d = r ^ 1;
        const int k1 = (t + 1) << 6;
        ITER(r, d, k1, 1, 5, 7, 5, 7, 3, 3);
    }
    {   // tail: no staging -> drain counts (r9 bug fix)
        const int r = (nt - 1) & 1;
        ITER(r, r ^ 1, 0, 0, 5, 4, 1, 0, 3, 0);
    }
#undef GLD
#undef SA_
#undef SB_
#undef VMW_
#undef VMW
#undef LGK0
#undef SBAR
#undef SCB
#undef LOADB
#undef LOADA
#undef MF
#undef ITER

    const int lr = (l >> 4) * 4;
    const int lc = l & 15;
    #pragma unroll
    for (int mf = 0; mf < AM; mf++) {
        #pragma unroll
        for (int i = 0; i < 4; i++) {
            const int row = m0 + wr * (AM * 16) + mf * 16 + lr + i;
            #pragma unroll
            for (int ni = 0; ni < 4; ni++) {
                const int col = n0 + wc * 64 + ni * 16 + lc;
                float v = acc[mf][ni][i] * scale;
                if (BIAS == 1) v += bias[col];
                if (BIAS == 2) v += bias[row];
                const long ci = (long)bz * sC + (long)row * ldC + col;
                if (OUTF32) ((float*)Cv)[ci] = v;
                else        ((u16*)Cv)[ci] = f2b(v);
            }
        }
    }
}

// ------- row softmax: 1024 f32 in -> 1024 bf16 written IN-PLACE (row stride 2048 u16) -------
__global__ __launch_bounds__(256) void k_softmax(float* __restrict__ sc) {
    __shared__ float red[8];
    const int r = blockIdx.x;
    const int t = threadIdx.x;
    const int w = t >> 6;
    float* p = sc + (long)r * 1024;
    f32x4 v = reinterpret_cast<const f32x4*>(p)[t];
    float m = fmaxf(fmaxf(v.x, v.y), fmaxf(v.z, v.w));
    #pragma unroll
    for (int d = 32; d >= 1; d >>= 1) m = fmaxf(m, __shfl_xor(m, d));
    if ((t & 63) == 0) red[w] = m;
    __syncthreads();
    m = fmaxf(fmaxf(red[0], red[1]), fmaxf(red[2], red[3]));
    f32x4 e;
    e.x = __expf(v.x - m); e.y = __expf(v.y - m);
    e.z = __expf(v.z - m); e.w = __expf(v.w - m);
    float s = e.x + e.y + e.z + e.w;
    #pragma unroll
    for (int d = 32; d >= 1; d >>= 1) s += __shfl_xor(s, d);
    if ((t & 63) == 0) red[4 + w] = s;
    __syncthreads();
    s = red[4] + red[5] + red[6] + red[7];
    const float inv = 1.0f / s;
    ushort4 o;
    o.x = f2b(e.x * inv); o.y = f2b(e.y * inv);
    o.z = f2b(e.z * inv); o.w = f2b(e.w * inv);
    reinterpret_cast<ushort4*>(reinterpret_cast<u16*>(sc) + (long)r * 2048)[t] = o;
}

// ---------------- LayerNorm over D=512, one wave per row ----------------
__global__ __launch_bounds__(256) void k_layernorm(const float* __restrict__ in,
                                                   const float* __restrict__ g,
                                                   const float* __restrict__ be,
                                                   float* __restrict__ of,
                                                   u16* __restrict__ ob) {
    const int w = threadIdx.x >> 6;
    const int l = threadIdx.x & 63;
    const long row = (long)blockIdx.x * 4 + w;
    const float* p = in + row * 512;
    f32x4 v0 = *reinterpret_cast<const f32x4*>(p + l * 4);
    f32x4 v1 = *reinterpret_cast<const f32x4*>(p + 256 + l * 4);
    float s = v0.x + v0.y + v0.z + v0.w + v1.x + v1.y + v1.z + v1.w;
    float q = v0.x * v0.x + v0.y * v0.y + v0.z * v0.z + v0.w * v0.w
            + v1.x * v1.x + v1.y * v1.y + v1.z * v1.z + v1.w * v1.w;
    #pragma unroll
    for (int d = 32; d >= 1; d >>= 1) { s += __shfl_xor(s, d); q += __shfl_xor(q, d); }
    const float mean = s * (1.0f / 512.0f);
    const float var = q * (1.0f / 512.0f) - mean * mean;
    const float inv = rsqrtf(var + 1e-5f);
    f32x4 ga = *reinterpret_cast<const f32x4*>(g + l * 4);
    f32x4 gb = *reinterpret_cast<const f32x4*>(g + 256 + l * 4);
    f32x4 ba = *reinterpret_cast<const f32x4*>(be + l * 4);
    f32x4 bb = *reinterpret_cast<const f32x4*>(be + 256 + l * 4);
    f32x4 o0 = (v0 - mean) * inv * ga + ba;
    f32x4 o1 = (v1 - mean) * inv * gb + bb;
    *reinterpret_cast<f32x4*>(of + row * 512 + l * 4) = o0;
    *reinterpret_cast<f32x4*>(of + row * 512 + 256 + l * 4) = o1;
    if (ob) {
        ushort4 p0, p1;
        p0.x = f2b(o0.x); p0.y = f2b(o0.y); p0.z = f2b(o0.z); p0.w = f2b(o0.w);
        p1.x = f2b(o1.x); p1.y = f2b(o1.y); p1.z = f2b(o1.z); p1.w = f2b(o1.w);
        *reinterpret_cast<ushort4*>(ob + row * 512 + l * 4) = p0;
        *reinterpret_cast<ushort4*>(ob + row * 512 + 256 + l * 4) = p1;
    }
}

extern "C" void kernel_launch(void* const* d_in, const int* in_sizes, int n_in,
                              void* d_out, int out_size, void* d_ws, size_t ws_size,
                              hipStream_t stream) {
    const float* x   = (const float*)d_in[0];
    const float* Wq  = (const float*)d_in[1];
    const float* bq  = (const float*)d_in[2];
    const float* Wk  = (const float*)d_in[3];
    const float* bk  = (const float*)d_in[4];
    const float* Wv  = (const float*)d_in[5];
    const float* bv  = (const float*)d_in[6];
    const float* Wo  = (const float*)d_in[7];
    const float* bo  = (const float*)d_in[8];
    const float* g0  = (const float*)d_in[9];
    const float* be0 = (const float*)d_in[10];
    const float* W1  = (const float*)d_in[11];
    const float* b1  = (const float*)d_in[12];
    const float* W2  = (const float*)d_in[13];
    const float* b2  = (const float*)d_in[14];
    const float* g1  = (const float*)d_in[15];
    const float* be1 = (const float*)d_in[16];
    float* out = (float*)d_out;

    // ---- workspace layout, peak 194.0 MB ----
    char* ws = (char*)d_ws;
    u16*   xb     = (u16*)(ws + 0);
    u16*   Wqb    = (u16*)(ws + 8388608);      // [Wq;Wk] contiguous
    u16*   Wvb    = (u16*)(ws + 16777216);
    u16*   Wob    = (u16*)(ws + 20971520);
    u16*   W1b    = (u16*)(ws + 25165824);
    u16*   W2b    = (u16*)(ws + 25690112);
    u16*   QKb    = (u16*)(ws + 26214400);     // [8192,8192] bf16
    u16*   VTb    = QKb;
    float* hsum   = (float*)(ws + 26214400);
    float* hf     = (float*)(ws + 42991616);
    u16*   hb     = (u16*)(ws + 59768832);
    u16*   ff1b   = (u16*)(ws + 68157440);
    float* t2     = (float*)(ws + 76546048);
    u16*   sdpab  = (u16*)(ws + 93323264);
    float* scores = (float*)(ws + 160432128);
    u16*   attnb  = (u16*)scores;
    float* bqk    = (float*)(ws + 160432128);

    hipMemcpyAsync(bqk,        bq, 4096 * 4, hipMemcpyDeviceToDevice, stream);
    hipMemcpyAsync(bqk + 4096, bk, 4096 * 4, hipMemcpyDeviceToDevice, stream);

    k_convert<<<4096, 256, 0, stream>>>(x, xb, 1048576);
    k_convert_w<<<8704, 256, 0, stream>>>(Wq, Wk, Wv, Wo, W1, W2, Wqb);

    const float scl = 0.044194173824159216f; // 1/sqrt(512)
    const size_t LDS_A8 = 131072;  // AM=8: 256x256
    const size_t LDS_A4 = 98304;   // AM=4: 128x256

    // [Q|K] = x·[Wq;Wk]^T + [bq;bk]
    gemm_nt256<8,1,0><<<dim3(32,32,1), 512, LDS_A8, stream>>>(xb,0, Wqb,0, bqk, QKb,0, 512,512,8192, 512, 1.0f);
    // scores[b] = (Q[b]·K[b]^T)/sqrt(512)
    gemm_nt256<4,0,1><<<dim3(4,8,8), 512, LDS_A4, stream>>>(QKb,8388608, QKb+4096,8388608, nullptr, scores,1048576, 8192,8192,1024, 4096, scl);
    // attn = softmax(scores) in-place
    k_softmax<<<8192, 256, 0, stream>>>(scores);
    // V^T[b] = Wv·x[b]^T + bv(row)
    gemm_nt256<8,2,0><<<dim3(4,16,8), 512, LDS_A8, stream>>>(Wvb,0, xb,524288, bv, VTb,4194304, 512,512,1024, 512, 1.0f);
    // sdpa[b] = attn[b]·(V^T[b])^T
    gemm_nt256<8,0,0><<<dim3(16,4,8), 512, LDS_A8, stream>>>(attnb,2097152, VTb,4194304, nullptr, sdpab,4194304, 2048,1024,4096, 1024, 1.0f);
    // hsum = sdpa·Wo^T + bo + x
    gemm_nt<1,0,1,1><<<dim3(4,64,1), 256, 0, stream>>>(sdpab,0, Wob,0, bo, x,0, hsum,0, 4096,4096,512, 4096, 1.0f);
    // h = LN(hsum)
    k_layernorm<<<2048, 256, 0, stream>>>(hsum, g0, be0, hf, hb);
    // ff1 = relu(h·W1^T + b1)
    gemm_nt<1,1,0,0><<<dim3(4,64,1), 256, 0, stream>>>(hb,0, W1b,0, b1, nullptr,0, ff1b,0, 512,512,512, 512, 1.0f);
    // t2 = ff1·W2^T + b2 + h
    gemm_nt<1,0,1,1><<<dim3(4,64,1), 256, 0, stream>>>(ff1b,0, W2b,0, b2, hf,0, t2,0, 512,512,512, 512, 1.0f);
    // out = LN(t2)
    k_layernorm<<<2048, 256, 0, stream>>>(t2, g1, be1, out, nullptr);
}

// Round 11
// 554.107 us; speedup vs baseline: 1.5574x; 1.0670x over previous
//
#include <hip/hip_runtime.h>

typedef unsigned short u16;
typedef unsigned int u32;
typedef float f32x4 __attribute__((ext_vector_type(4)));
typedef __bf16 bf16x8 __attribute__((ext_vector_type(8)));

__device__ __forceinline__ u16 f2b(float f) {
    u32 b = __builtin_bit_cast(u32, f);
    b = b + 0x7FFFu + ((b >> 16) & 1u);
    return (u16)(b >> 16);
}

// ---------------- fp32 -> bf16 convert (4 elems/thread) ----------------
__global__ __launch_bounds__(256) void k_convert(const float* __restrict__ in,
                                                 u16* __restrict__ out, int n4) {
    int i = blockIdx.x * 256 + threadIdx.x;
    if (i >= n4) return;
    f32x4 v = reinterpret_cast<const f32x4*>(in)[i];
    ushort4 o;
    o.x = f2b(v.x); o.y = f2b(v.y); o.z = f2b(v.z); o.w = f2b(v.w);
    reinterpret_cast<ushort4*>(out)[i] = o;
}

// ------ fused weight convert: Wq,Wk,Wv,Wo + W1,W2 -> contiguous dst ----
__global__ __launch_bounds__(256) void k_convert_w(const float* __restrict__ wq, const float* __restrict__ wk,
                                                   const float* __restrict__ wv, const float* __restrict__ wo,
                                                   const float* __restrict__ w1, const float* __restrict__ w2,
                                                   u16* __restrict__ dst) {
    const int b = blockIdx.x;
    const float* src;
    long dof;
    int li;
    if (b < 8192) {
        const int wsel = b >> 11;
        li = (b & 2047) * 256 + threadIdx.x;
        src = wsel == 0 ? wq : wsel == 1 ? wk : wsel == 2 ? wv : wo;
        dof = (long)wsel * 2097152 + (long)li * 4;
    } else {
        const int wsel = (b - 8192) >> 8;
        li = ((b - 8192) & 255) * 256 + threadIdx.x;
        src = wsel == 0 ? w1 : w2;
        dof = 8388608 + (long)wsel * 262144 + (long)li * 4;
    }
    f32x4 v = reinterpret_cast<const f32x4*>(src)[li];
    ushort4 o;
    o.x = f2b(v.x); o.y = f2b(v.y); o.z = f2b(v.z); o.w = f2b(v.w);
    *reinterpret_cast<ushort4*>(dst + dof) = o;
}

// ============ 128^2 NT bf16 GEMM — r10: counted-vmcnt cross-buffer pipeline (T3+T4) ============
// 256 thr (4 waves 2x2), BM=BN=128, BK=64. Tile t in buf t&1; tile t+1 staged to buf^1.
// Stage groups per wave (FIFO): G0(ks0) = {A q0,q2; B q0,q2}, G1(ks1) = {A q1,q3; B q1,q3} (4 each).
// Ledger: prologue 8 outstanding; steady waits vmcnt(4)/vmcnt(4); TAIL (no stage): vmcnt(4)/vmcnt(0).
// Per phase: wait -> s_barrier -> ds_read(buf r) || stage(buf d) -> lgkmcnt(0) -> MFMA x16.
// Cross-wave slot reads safe: symmetric per-wave counts + per-phase barrier.
template<int BIAS /*0 none,1 col,2 row*/, int ACT, int OUTF32, int RES>
__global__ __launch_bounds__(256, 2) void gemm_nt(
    const u16* __restrict__ A, long sA,
    const u16* __restrict__ B, long sB,
    const float* __restrict__ bias,
    const float* __restrict__ res, long sRes,
    void* __restrict__ Cv, long sC,
    int ldA, int ldB, int ldC, int K, float scale)
{
    __shared__ u16 Al[16384];   // 2 buffers x 8192
    __shared__ u16 Bl[16384];
    const int tid = threadIdx.x;

    const int nx = gridDim.x, ny = gridDim.y;
    const int nwg = nx * ny * (int)gridDim.z;
    int orig = blockIdx.x + nx * (blockIdx.y + ny * blockIdx.z);
    int wg = ((nwg & 7) == 0) ? ((orig & 7) * (nwg >> 3) + (orig >> 3)) : orig;
    const int bx = wg % nx;
    const int tmp = wg / nx;
    const int by = tmp % ny;
    const int bz = tmp / ny;

    const int m0 = by * 128;
    const int n0 = bx * 128;
    A += (long)bz * sA;
    B += (long)bz * sB;
    const int l = tid & 63;
    const int w = tid >> 6;
    const int wr = w >> 1, wc = w & 1;

    const int fr = l & 15;
    const int fk = (l >> 4) * 8;
    const u16* gA = A + (long)(m0 + w * 32 + fr) * ldA + fk;
    const u16* gB = B + (long)(n0 + w * 32 + fr) * ldB + fk;

    f32x4 acc[4][4] = {};
    const int nt = K >> 6;

#define GLD(src, dst) __builtin_amdgcn_global_load_lds(                          \
        (const __attribute__((address_space(1))) u32*)(src),                     \
        (__attribute__((address_space(3))) u32*)(dst), 16, 0, 0)
#define SA(d, k0, q) GLD(gA + (k0) + ((q) & 1) * 32 + (long)((q) >> 1) * 16 * ldA, \
                         Al + (d) * 8192 + w * 2048 + (q) * 512)
#define SB(d, k0, q) GLD(gB + (k0) + ((q) & 1) * 32 + (long)((q) >> 1) * 16 * ldB, \
                         Bl + (d) * 8192 + w * 2048 + (q) * 512)
#define VMW_(n) asm volatile("s_waitcnt vmcnt(" #n ")" ::: "memory")
#define VMW(n) VMW_(n)
#define LGK0() asm volatile("s_waitcnt lgkmcnt(0)" ::: "memory")
#define SBAR() __builtin_amdgcn_s_barrier()
#define SCB() __builtin_amdgcn_sched_barrier(0)
#define PHASE(r, d, k1, ks, ST, V)                                               \
    {                                                                            \
        VMW(V);                                                                  \
        SBAR(); SCB();                                                           \
        bf16x8 af[4], bfr[4];                                                    \
        _Pragma("unroll")                                                        \
        for (int t4 = 0; t4 < 4; t4++) {                                         \
            af[t4]  = *reinterpret_cast<const bf16x8*>(                          \
                &Al[(r) * 8192 + ((wr * 4 + t4) * 2 + (ks)) * 512 + l * 8]);     \
            bfr[t4] = *reinterpret_cast<const bf16x8*>(                          \
                &Bl[(r) * 8192 + ((wc * 4 + t4) * 2 + (ks)) * 512 + l * 8]);     \
        }                                                                        \
        if (ST) { SA(d, k1, 0 + (ks)); SA(d, k1, 2 + (ks));                      \
                  SB(d, k1, 0 + (ks)); SB(d, k1, 2 + (ks)); }                    \
        LGK0(); SCB();                                                           \
        __builtin_amdgcn_s_setprio(1);                                           \
        _Pragma("unroll")                                                        \
        for (int mt = 0; mt < 4; mt++)                                           \
            _Pragma("unroll")                                                    \
            for (int nt2 = 0; nt2 < 4; nt2++)                                    \
                acc[mt][nt2] = __builtin_amdgcn_mfma_f32_16x16x32_bf16(          \
                    af[mt], bfr[nt2], acc[mt][nt2], 0, 0, 0);                    \
        __builtin_amdgcn_s_setprio(0);                                           \
    }

    // prologue: stage tile 0 into buf 0, FIFO order G0 (ks0) then G1 (ks1)
    SA(0, 0, 0); SA(0, 0, 2); SB(0, 0, 0); SB(0, 0, 2);
    SA(0, 0, 1); SA(0, 0, 3); SB(0, 0, 1); SB(0, 0, 3);

    for (int t = 0; t < nt - 1; ++t) {
        const int r = t & 1;
        const int d = r ^ 1;
        const int k1 = (t + 1) << 6;
        PHASE(r, d, k1, 0, 1, 4);
        PHASE(r, d, k1, 1, 1, 4);
    }
    {   // tail: no staging -> drain counts
        const int r = (nt - 1) & 1;
        PHASE(r, r ^ 1, 0, 0, 0, 4);
        PHASE(r, r ^ 1, 0, 1, 0, 0);
    }
#undef GLD
#undef SA
#undef SB
#undef VMW_
#undef VMW
#undef LGK0
#undef SBAR
#undef SCB
#undef PHASE

    const int lr = (l >> 4) * 4;
    const int lc = l & 15;
    #pragma unroll
    for (int mt = 0; mt < 4; mt++) {
        #pragma unroll
        for (int i = 0; i < 4; i++) {
            const int row = m0 + wr * 64 + mt * 16 + lr + i;
            #pragma unroll
            for (int nt2 = 0; nt2 < 4; nt2++) {
                const int col = n0 + wc * 64 + nt2 * 16 + lc;
                float v = acc[mt][nt2][i] * scale;
                if (BIAS == 1) v += bias[col];
                if (BIAS == 2) v += bias[row];
                if (ACT) v = fmaxf(v, 0.0f);
                if (RES) v += res[(long)bz * sRes + (long)row * ldC + col];
                const long ci = (long)bz * sC + (long)row * ldC + col;
                if (OUTF32) ((float*)Cv)[ci] = v;
                else        ((u16*)Cv)[ci] = f2b(v);
            }
        }
    }
}

// ============ big-tile NT bf16 GEMM — T3+T4 counted-vmcnt pipeline, tail-corrected (r9) ============
template<int AM, int BIAS /*0,1 col,2 row*/, int OUTF32>
__global__ __launch_bounds__(512, 2) void gemm_nt256(
    const u16* __restrict__ A, long sA,
    const u16* __restrict__ B, long sB,
    const float* __restrict__ bias,
    void* __restrict__ Cv, long sC,
    int ldA, int ldB, int ldC, int K, float scale)
{
    extern __shared__ u16 lds[];
    constexpr int AS = AM * 2048;
    constexpr int BOFF = 2 * AS;
    const int tid = threadIdx.x;

    const int nx = gridDim.x, ny = gridDim.y;
    const int nwg = nx * ny * (int)gridDim.z;
    int orig = blockIdx.x + nx * (blockIdx.y + ny * blockIdx.z);
    int wg = ((nwg & 7) == 0) ? ((orig & 7) * (nwg >> 3) + (orig >> 3)) : orig;
    const int bx = wg % nx;
    const int tmp = wg / nx;
    const int by = tmp % ny;
    const int bz = tmp / ny;

    const int m0 = by * (AM * 32);
    const int n0 = bx * 256;
    A += (long)bz * sA;
    B += (long)bz * sB;
    const int l = tid & 63;
    const int w = tid >> 6;
    const int wr = w >> 2, wc = w & 3;
    const int fr = l & 15;
    const int fk = (l >> 4) * 8;

    const int mtA0 = (AM == 8) ? ((w & 3) + (w >> 2) * 8) : w;
    const int mtA1 = (AM == 8) ? (4 + (w & 3) + (w >> 2) * 8) : 0;

    f32x4 acc[AM][4] = {};
    const int nt = K >> 6;

#define GLD(src, dst) __builtin_amdgcn_global_load_lds(                          \
        (const __attribute__((address_space(1))) u32*)(src),                     \
        (__attribute__((address_space(3))) u32*)(dst), 16, 0, 0)
#define SA_(d, k1, mt, ksc) GLD(A + (long)(m0 + (mt) * 16 + fr) * ldA + (k1) + (ksc) * 32 + fk, \
                                lds + (d) * AS + ((mt) * 2 + (ksc)) * 512 + l * 8)
#define SB_(d, k1, mt, ksc) GLD(B + (long)(n0 + (mt) * 16 + fr) * ldB + (k1) + (ksc) * 32 + fk, \
                                lds + BOFF + (d) * 16384 + ((mt) * 2 + (ksc)) * 512 + l * 8)
#define VMW_(n) asm volatile("s_waitcnt vmcnt(" #n ")" ::: "memory")
#define VMW(n) VMW_(n)
#define LGK0()  asm volatile("s_waitcnt lgkmcnt(0)" ::: "memory")
#define SBAR() __builtin_amdgcn_s_barrier()
#define SCB() __builtin_amdgcn_sched_barrier(0)

#define LOADB(r, ksc)                                                            \
    _Pragma("unroll")                                                            \
    for (int t4 = 0; t4 < 4; t4++)                                               \
        bfv[t4] = *reinterpret_cast<const bf16x8*>(                              \
            lds + BOFF + (r) * 16384 + ((wc * 4 + t4) * 2 + (ksc)) * 512 + l * 8);
#define LOADA(r, mh, ksc)                                                        \
    _Pragma("unroll")                                                            \
    for (int t4 = 0; t4 < AM / 2; t4++)                                          \
        af[t4] = *reinterpret_cast<const bf16x8*>(                               \
            lds + (r) * AS + ((wr * AM + (mh) * (AM / 2) + t4) * 2 + (ksc)) * 512 + l * 8);
#define MF(mh)                                                                   \
    __builtin_amdgcn_s_setprio(1);                                               \
    _Pragma("unroll")                                                            \
    for (int mi = 0; mi < AM / 2; mi++)                                          \
        _Pragma("unroll")                                                        \
        for (int ni = 0; ni < 4; ni++)                                           \
            acc[(mh) * (AM / 2) + mi][ni] = __builtin_amdgcn_mfma_f32_16x16x32_bf16( \
                af[mi], bfv[ni], acc[(mh) * (AM / 2) + mi][ni], 0, 0, 0);        \
    __builtin_amdgcn_s_setprio(0);

#define ITER(r, d, k1, ST, V0_8, V1_8, V2_8, V3_8, V0_4, V2_4)                   \
    {                                                                            \
        bf16x8 bfv[4], af[AM / 2];                                               \
        if constexpr (AM == 8) { VMW(V0_8); } else { VMW(V0_4); }                \
        SBAR(); SCB();                                                           \
        LOADB(r, 0); LOADA(r, 0, 0);                                             \
        if (ST) { SA_(d, k1, mtA0, 0); SB_(d, k1, w, 0); SB_(d, k1, 8 + w, 0); } \
        LGK0(); SCB();                                                           \
        MF(0);                                                                   \
        if constexpr (AM == 8) { VMW(V1_8); SBAR(); SCB(); }                     \
        LOADA(r, 1, 0);                                                          \
        if constexpr (AM == 8) { if (ST) SA_(d, k1, mtA1, 0); }                  \
        LGK0(); SCB();                                                           \
        MF(1);                                                                   \
        if constexpr (AM == 8) { VMW(V2_8); } else { VMW(V2_4); }                \
        SBAR(); SCB();                                                           \
        LOADB(r, 1); LOADA(r, 0, 1);                                             \
        if (ST) { SA_(d, k1, mtA0, 1); SB_(d, k1, w, 1); SB_(d, k1, 8 + w, 1); } \
        LGK0(); SCB();                                                           \
        MF(0);                                                                   \
        if constexpr (AM == 8) { VMW(V3_8); SBAR(); SCB(); }                     \
        LOADA(r, 1, 1);                                                          \
        if constexpr (AM == 8) { if (ST) SA_(d, k1, mtA1, 1); }                  \
        LGK0(); SCB();                                                           \
        MF(1);                                                                   \
    }

    {
        SA_(0, 0, mtA0, 0); SB_(0, 0, w, 0); SB_(0, 0, 8 + w, 0);
        if constexpr (AM == 8) SA_(0, 0, mtA1, 0);
        SA_(0, 0, mtA0, 1); SB_(0, 0, w, 1); SB_(0, 0, 8 + w, 1);
        if constexpr (AM == 8) SA_(0, 0, mtA1, 1);
    }

    for (int t = 0; t < nt - 1; ++t) {
        const int r = t & 1;
        const int d = r ^ 1;
        const int k1 = (t + 1) << 6;
        ITER(r, d, k1, 1, 5, 7, 5, 7, 3, 3);
    }
    {   // tail: no staging -> drain counts
        const int r = (nt - 1) & 1;
        ITER(r, r ^ 1, 0, 0, 5, 4, 1, 0, 3, 0);
    }
#undef GLD
#undef SA_
#undef SB_
#undef VMW_
#undef VMW
#undef LGK0
#undef SBAR
#undef SCB
#undef LOADB
#undef LOADA
#undef MF
#undef ITER

    const int lr = (l >> 4) * 4;
    const int lc = l & 15;
    #pragma unroll
    for (int mf = 0; mf < AM; mf++) {
        #pragma unroll
        for (int i = 0; i < 4; i++) {
            const int row = m0 + wr * (AM * 16) + mf * 16 + lr + i;
            #pragma unroll
            for (int ni = 0; ni < 4; ni++) {
                const int col = n0 + wc * 64 + ni * 16 + lc;
                float v = acc[mf][ni][i] * scale;
                if (BIAS == 1) v += bias[col];
                if (BIAS == 2) v += bias[row];
                const long ci = (long)bz * sC + (long)row * ldC + col;
                if (OUTF32) ((float*)Cv)[ci] = v;
                else        ((u16*)Cv)[ci] = f2b(v);
            }
        }
    }
}

// ------- row softmax: 1024 f32 in -> 1024 bf16 written IN-PLACE (row stride 2048 u16) -------
__global__ __launch_bounds__(256) void k_softmax(float* __restrict__ sc) {
    __shared__ float red[8];
    const int r = blockIdx.x;
    const int t = threadIdx.x;
    const int w = t >> 6;
    float* p = sc + (long)r * 1024;
    f32x4 v = reinterpret_cast<const f32x4*>(p)[t];
    float m = fmaxf(fmaxf(v.x, v.y), fmaxf(v.z, v.w));
    #pragma unroll
    for (int d = 32; d >= 1; d >>= 1) m = fmaxf(m, __shfl_xor(m, d));
    if ((t & 63) == 0) red[w] = m;
    __syncthreads();
    m = fmaxf(fmaxf(red[0], red[1]), fmaxf(red[2], red[3]));
    f32x4 e;
    e.x = __expf(v.x - m); e.y = __expf(v.y - m);
    e.z = __expf(v.z - m); e.w = __expf(v.w - m);
    float s = e.x + e.y + e.z + e.w;
    #pragma unroll
    for (int d = 32; d >= 1; d >>= 1) s += __shfl_xor(s, d);
    if ((t & 63) == 0) red[4 + w] = s;
    __syncthreads();
    s = red[4] + red[5] + red[6] + red[7];
    const float inv = 1.0f / s;
    ushort4 o;
    o.x = f2b(e.x * inv); o.y = f2b(e.y * inv);
    o.z = f2b(e.z * inv); o.w = f2b(e.w * inv);
    reinterpret_cast<ushort4*>(reinterpret_cast<u16*>(sc) + (long)r * 2048)[t] = o;
}

// ---------------- LayerNorm over D=512, one wave per row ----------------
__global__ __launch_bounds__(256) void k_layernorm(const float* __restrict__ in,
                                                   const float* __restrict__ g,
                                                   const float* __restrict__ be,
                                                   float* __restrict__ of,
                                                   u16* __restrict__ ob) {
    const int w = threadIdx.x >> 6;
    const int l = threadIdx.x & 63;
    const long row = (long)blockIdx.x * 4 + w;
    const float* p = in + row * 512;
    f32x4 v0 = *reinterpret_cast<const f32x4*>(p + l * 4);
    f32x4 v1 = *reinterpret_cast<const f32x4*>(p + 256 + l * 4);
    float s = v0.x + v0.y + v0.z + v0.w + v1.x + v1.y + v1.z + v1.w;
    float q = v0.x * v0.x + v0.y * v0.y + v0.z * v0.z + v0.w * v0.w
            + v1.x * v1.x + v1.y * v1.y + v1.z * v1.z + v1.w * v1.w;
    #pragma unroll
    for (int d = 32; d >= 1; d >>= 1) { s += __shfl_xor(s, d); q += __shfl_xor(q, d); }
    const float mean = s * (1.0f / 512.0f);
    const float var = q * (1.0f / 512.0f) - mean * mean;
    const float inv = rsqrtf(var + 1e-5f);
    f32x4 ga = *reinterpret_cast<const f32x4*>(g + l * 4);
    f32x4 gb = *reinterpret_cast<const f32x4*>(g + 256 + l * 4);
    f32x4 ba = *reinterpret_cast<const f32x4*>(be + l * 4);
    f32x4 bb = *reinterpret_cast<const f32x4*>(be + 256 + l * 4);
    f32x4 o0 = (v0 - mean) * inv * ga + ba;
    f32x4 o1 = (v1 - mean) * inv * gb + bb;
    *reinterpret_cast<f32x4*>(of + row * 512 + l * 4) = o0;
    *reinterpret_cast<f32x4*>(of + row * 512 + 256 + l * 4) = o1;
    if (ob) {
        ushort4 p0, p1;
        p0.x = f2b(o0.x); p0.y = f2b(o0.y); p0.z = f2b(o0.z); p0.w = f2b(o0.w);
        p1.x = f2b(o1.x); p1.y = f2b(o1.y); p1.z = f2b(o1.z); p1.w = f2b(o1.w);
        *reinterpret_cast<ushort4*>(ob + row * 512 + l * 4) = p0;
        *reinterpret_cast<ushort4*>(ob + row * 512 + 256 + l * 4) = p1;
    }
}

extern "C" void kernel_launch(void* const* d_in, const int* in_sizes, int n_in,
                              void* d_out, int out_size, void* d_ws, size_t ws_size,
                              hipStream_t stream) {
    const float* x   = (const float*)d_in[0];
    const float* Wq  = (const float*)d_in[1];
    const float* bq  = (const float*)d_in[2];
    const float* Wk  = (const float*)d_in[3];
    const float* bk  = (const float*)d_in[4];
    const float* Wv  = (const float*)d_in[5];
    const float* bv  = (const float*)d_in[6];
    const float* Wo  = (const float*)d_in[7];
    const float* bo  = (const float*)d_in[8];
    const float* g0  = (const float*)d_in[9];
    const float* be0 = (const float*)d_in[10];
    const float* W1  = (const float*)d_in[11];
    const float* b1  = (const float*)d_in[12];
    const float* W2  = (const float*)d_in[13];
    const float* b2  = (const float*)d_in[14];
    const float* g1  = (const float*)d_in[15];
    const float* be1 = (const float*)d_in[16];
    float* out = (float*)d_out;

    // ---- workspace layout, peak 194.0 MB ----
    char* ws = (char*)d_ws;
    u16*   xb     = (u16*)(ws + 0);
    u16*   Wqb    = (u16*)(ws + 8388608);      // [Wq;Wk] contiguous
    u16*   Wvb    = (u16*)(ws + 16777216);
    u16*   Wob    = (u16*)(ws + 20971520);
    u16*   W1b    = (u16*)(ws + 25165824);
    u16*   W2b    = (u16*)(ws + 25690112);
    u16*   QKb    = (u16*)(ws + 26214400);     // [8192,8192] bf16
    u16*   VTb    = QKb;
    float* hsum   = (float*)(ws + 26214400);
    float* hf     = (float*)(ws + 42991616);
    u16*   hb     = (u16*)(ws + 59768832);
    u16*   ff1b   = (u16*)(ws + 68157440);
    float* t2     = (float*)(ws + 76546048);
    u16*   sdpab  = (u16*)(ws + 93323264);
    float* scores = (float*)(ws + 160432128);
    u16*   attnb  = (u16*)scores;
    float* bqk    = (float*)(ws + 160432128);

    hipMemcpyAsync(bqk,        bq, 4096 * 4, hipMemcpyDeviceToDevice, stream);
    hipMemcpyAsync(bqk + 4096, bk, 4096 * 4, hipMemcpyDeviceToDevice, stream);

    k_convert<<<4096, 256, 0, stream>>>(x, xb, 1048576);
    k_convert_w<<<8704, 256, 0, stream>>>(Wq, Wk, Wv, Wo, W1, W2, Wqb);

    const float scl = 0.044194173824159216f; // 1/sqrt(512)
    const size_t LDS_A8 = 131072;  // AM=8: 256x256
    const size_t LDS_A4 = 98304;   // AM=4: 128x256

    // [Q|K] = x·[Wq;Wk]^T + [bq;bk]
    gemm_nt256<8,1,0><<<dim3(32,32,1), 512, LDS_A8, stream>>>(xb,0, Wqb,0, bqk, QKb,0, 512,512,8192, 512, 1.0f);
    // scores[b] = (Q[b]·K[b]^T)/sqrt(512)
    gemm_nt256<4,0,1><<<dim3(4,8,8), 512, LDS_A4, stream>>>(QKb,8388608, QKb+4096,8388608, nullptr, scores,1048576, 8192,8192,1024, 4096, scl);
    // attn = softmax(scores) in-place
    k_softmax<<<8192, 256, 0, stream>>>(scores);
    // V^T[b] = Wv·x[b]^T + bv(row)
    gemm_nt256<8,2,0><<<dim3(4,16,8), 512, LDS_A8, stream>>>(Wvb,0, xb,524288, bv, VTb,4194304, 512,512,1024, 512, 1.0f);
    // sdpa[b] = attn[b]·(V^T[b])^T
    gemm_nt256<8,0,0><<<dim3(16,4,8), 512, LDS_A8, stream>>>(attnb,2097152, VTb,4194304, nullptr, sdpab,4194304, 2048,1024,4096, 1024, 1.0f);
    // hsum = sdpa·Wo^T + bo + x   (pipelined 128^2 kernel)
    gemm_nt<1,0,1,1><<<dim3(4,64,1), 256, 0, stream>>>(sdpab,0, Wob,0, bo, x,0, hsum,0, 4096,4096,512, 4096, 1.0f);
    // h = LN(hsum)
    k_layernorm<<<2048, 256, 0, stream>>>(hsum, g0, be0, hf, hb);
    // ff1 = relu(h·W1^T + b1)
    gemm_nt<1,1,0,0><<<dim3(4,64,1), 256, 0, stream>>>(hb,0, W1b,0, b1, nullptr,0, ff1b,0, 512,512,512, 512, 1.0f);
    // t2 = ff1·W2^T + b2 + h
    gemm_nt<1,0,1,1><<<dim3(4,64,1), 256, 0, stream>>>(ff1b,0, W2b,0, b2, hf,0, t2,0, 512,512,512, 512, 1.0f);
    // out = LN(t2)
    k_layernorm<<<2048, 256, 0, stream>>>(t2, g1, be1, out, nullptr);
}

// Round 12
// 314.316 us; speedup vs baseline: 2.7456x; 1.7629x over previous
//
#include <hip/hip_runtime.h>

typedef unsigned short u16;
typedef unsigned int u32;
typedef float f32x4 __attribute__((ext_vector_type(4)));
typedef __bf16 bf16x8 __attribute__((ext_vector_type(8)));

__device__ __forceinline__ u16 f2b(float f) {
    u32 b = __builtin_bit_cast(u32, f);
    b = b + 0x7FFFu + ((b >> 16) & 1u);
    return (u16)(b >> 16);
}

// ---------------- fp32 -> bf16 convert (4 elems/thread) ----------------
__global__ __launch_bounds__(256) void k_convert(const float* __restrict__ in,
                                                 u16* __restrict__ out, int n4) {
    int i = blockIdx.x * 256 + threadIdx.x;
    if (i >= n4) return;
    f32x4 v = reinterpret_cast<const f32x4*>(in)[i];
    ushort4 o;
    o.x = f2b(v.x); o.y = f2b(v.y); o.z = f2b(v.z); o.w = f2b(v.w);
    reinterpret_cast<ushort4*>(out)[i] = o;
}

// ---------------- f32 [R,C] -> bf16 [C,R] transpose (64x64 LDS tiles, batched via z) -------
__global__ __launch_bounds__(256) void k_transpose(const float* __restrict__ src, u16* __restrict__ dst,
                                                   int R, int C, long sS, long sD) {
    __shared__ float tile[64][65];
    src += (long)blockIdx.z * sS;
    dst += (long)blockIdx.z * sD;
    const int c0 = blockIdx.x * 64, r0 = blockIdx.y * 64;
    const int col = threadIdx.x & 63, row = threadIdx.x >> 6;   // row 0..3
    #pragma unroll
    for (int i = 0; i < 16; i++)
        tile[row + i * 4][col] = src[(long)(r0 + row + i * 4) * C + c0 + col];
    __syncthreads();
    #pragma unroll
    for (int i = 0; i < 16; i++)
        dst[(long)(c0 + row + i * 4) * R + r0 + col] = f2b(tile[col][row + i * 4]);
}

// --------- v512[c] = sum_r W[r,c]*b[r]   (W [4096,512] f32) ---------
__global__ __launch_bounds__(256) void k_colvec(const float* __restrict__ W, const float* __restrict__ b,
                                                float* __restrict__ out) {
    __shared__ float red[4];
    const int c = blockIdx.x;
    float s = 0.0f;
    for (int r = threadIdx.x; r < 4096; r += 256) s += W[(long)r * 512 + c] * b[r];
    #pragma unroll
    for (int d = 32; d >= 1; d >>= 1) s += __shfl_xor(s, d);
    if ((threadIdx.x & 63) == 0) red[threadIdx.x >> 6] = s;
    __syncthreads();
    if (threadIdx.x == 0) out[c] = red[0] + red[1] + red[2] + red[3];
}

// --------- w0[i] = dot(W[i,:4096], b) + b2[i]   (W [512,4096] f32) ---------
__global__ __launch_bounds__(256) void k_rowvec(const float* __restrict__ W, const float* __restrict__ b,
                                                const float* __restrict__ b2, float* __restrict__ out) {
    __shared__ float red[4];
    const int i = blockIdx.x;
    float s = 0.0f;
    for (int k = threadIdx.x; k < 4096; k += 256) s += W[(long)i * 4096 + k] * b[k];
    #pragma unroll
    for (int d = 32; d >= 1; d >>= 1) s += __shfl_xor(s, d);
    if ((threadIdx.x & 63) == 0) red[threadIdx.x >> 6] = s;
    __syncthreads();
    if (threadIdx.x == 0) out[i] = red[0] + red[1] + red[2] + red[3] + b2[i];
}

// --------- vfull[s] = dot(x[s,:512], v512)   (one wave per row) ---------
__global__ __launch_bounds__(256) void k_xv(const float* __restrict__ x, const float* __restrict__ v512,
                                            float* __restrict__ out) {
    const int w = threadIdx.x >> 6, l = threadIdx.x & 63;
    const long row = (long)blockIdx.x * 4 + w;
    float s = 0.0f;
    for (int j = l; j < 512; j += 64) s += x[row * 512 + j] * v512[j];
    #pragma unroll
    for (int d = 32; d >= 1; d >>= 1) s += __shfl_xor(s, d);
    if (l == 0) out[row] = s;
}

// ============ 128^2 NT bf16 GEMM — r10 counted-vmcnt pipeline + split-K/atomic option ============
// C[m,n] = scale * sum_k A[m,k]*B[n,k]  (+bias)(+relu)(+res). SPLITKLOG>0: bz = bm*2^S + kc,
// K = chunk length, A/B offset by kc*K along k, ATOM=1 atomicAdd f32 into C (C pre-zeroed).
// Schedule (verified r10): tile t in buf t&1; stage groups G(ks)=4 loads; steady vmcnt(4)/4;
// tail vmcnt(4)/0; per phase: wait -> s_barrier -> ds_read || stage -> lgkmcnt(0) -> MFMA x16.
template<int BIAS /*0 none,1 col,2 row*/, int ACT, int OUTF32, int RES, int SPLITKLOG = 0, int ATOM = 0>
__global__ __launch_bounds__(256, 2) void gemm_nt(
    const u16* __restrict__ A, long sA,
    const u16* __restrict__ B, long sB,
    const float* __restrict__ bias,
    const float* __restrict__ res, long sRes,
    void* __restrict__ Cv, long sC,
    int ldA, int ldB, int ldC, int K, float scale)
{
    __shared__ u16 Al[16384];   // 2 buffers x 8192
    __shared__ u16 Bl[16384];
    const int tid = threadIdx.x;

    const int nx = gridDim.x, ny = gridDim.y;
    const int nwg = nx * ny * (int)gridDim.z;
    int orig = blockIdx.x + nx * (blockIdx.y + ny * blockIdx.z);
    int wg = ((nwg & 7) == 0) ? ((orig & 7) * (nwg >> 3) + (orig >> 3)) : orig;
    const int bx = wg % nx;
    const int tmp = wg / nx;
    const int by = tmp % ny;
    const int bz = tmp / ny;

    int bm = bz, kc = 0;
    if constexpr (SPLITKLOG > 0) { kc = bz & ((1 << SPLITKLOG) - 1); bm = bz >> SPLITKLOG; }

    const int m0 = by * 128;
    const int n0 = bx * 128;
    A += (long)bm * sA + (long)kc * K;
    B += (long)bm * sB + (long)kc * K;
    const int l = tid & 63;
    const int w = tid >> 6;
    const int wr = w >> 1, wc = w & 1;

    const int fr = l & 15;
    const int fk = (l >> 4) * 8;
    const u16* gA = A + (long)(m0 + w * 32 + fr) * ldA + fk;
    const u16* gB = B + (long)(n0 + w * 32 + fr) * ldB + fk;

    f32x4 acc[4][4] = {};
    const int nt = K >> 6;

#define GLD(src, dst) __builtin_amdgcn_global_load_lds(                          \
        (const __attribute__((address_space(1))) u32*)(src),                     \
        (__attribute__((address_space(3))) u32*)(dst), 16, 0, 0)
#define SA(d, k0, q) GLD(gA + (k0) + ((q) & 1) * 32 + (long)((q) >> 1) * 16 * ldA, \
                         Al + (d) * 8192 + w * 2048 + (q) * 512)
#define SB(d, k0, q) GLD(gB + (k0) + ((q) & 1) * 32 + (long)((q) >> 1) * 16 * ldB, \
                         Bl + (d) * 8192 + w * 2048 + (q) * 512)
#define VMW_(n) asm volatile("s_waitcnt vmcnt(" #n ")" ::: "memory")
#define VMW(n) VMW_(n)
#define LGK0() asm volatile("s_waitcnt lgkmcnt(0)" ::: "memory")
#define SBAR() __builtin_amdgcn_s_barrier()
#define SCB() __builtin_amdgcn_sched_barrier(0)
#define PHASE(r, d, k1, ks, ST, V)                                               \
    {                                                                            \
        VMW(V);                                                                  \
        SBAR(); SCB();                                                           \
        bf16x8 af[4], bfr[4];                                                    \
        _Pragma("unroll")                                                        \
        for (int t4 = 0; t4 < 4; t4++) {                                         \
            af[t4]  = *reinterpret_cast<const bf16x8*>(                          \
                &Al[(r) * 8192 + ((wr * 4 + t4) * 2 + (ks)) * 512 + l * 8]);     \
            bfr[t4] = *reinterpret_cast<const bf16x8*>(                          \
                &Bl[(r) * 8192 + ((wc * 4 + t4) * 2 + (ks)) * 512 + l * 8]);     \
        }                                                                        \
        if (ST) { SA(d, k1, 0 + (ks)); SA(d, k1, 2 + (ks));                      \
                  SB(d, k1, 0 + (ks)); SB(d, k1, 2 + (ks)); }                    \
        LGK0(); SCB();                                                           \
        __builtin_amdgcn_s_setprio(1);                                           \
        _Pragma("unroll")                                                        \
        for (int mt = 0; mt < 4; mt++)                                           \
            _Pragma("unroll")                                                    \
            for (int nt2 = 0; nt2 < 4; nt2++)                                    \
                acc[mt][nt2] = __builtin_amdgcn_mfma_f32_16x16x32_bf16(          \
                    af[mt], bfr[nt2], acc[mt][nt2], 0, 0, 0);                    \
        __builtin_amdgcn_s_setprio(0);                                           \
    }

    // prologue: stage tile 0 into buf 0, FIFO order G0 (ks0) then G1 (ks1)
    SA(0, 0, 0); SA(0, 0, 2); SB(0, 0, 0); SB(0, 0, 2);
    SA(0, 0, 1); SA(0, 0, 3); SB(0, 0, 1); SB(0, 0, 3);

    for (int t = 0; t < nt - 1; ++t) {
        const int r = t & 1;
        const int d = r ^ 1;
        const int k1 = (t + 1) << 6;
        PHASE(r, d, k1, 0, 1, 4);
        PHASE(r, d, k1, 1, 1, 4);
    }
    {   // tail: no staging -> drain counts
        const int r = (nt - 1) & 1;
        PHASE(r, r ^ 1, 0, 0, 0, 4);
        PHASE(r, r ^ 1, 0, 1, 0, 0);
    }
#undef GLD
#undef SA
#undef SB
#undef VMW_
#undef VMW
#undef LGK0
#undef SBAR
#undef SCB
#undef PHASE

    const int lr = (l >> 4) * 4;
    const int lc = l & 15;
    #pragma unroll
    for (int mt = 0; mt < 4; mt++) {
        #pragma unroll
        for (int i = 0; i < 4; i++) {
            const int row = m0 + wr * 64 + mt * 16 + lr + i;
            #pragma unroll
            for (int nt2 = 0; nt2 < 4; nt2++) {
                const int col = n0 + wc * 64 + nt2 * 16 + lc;
                float v = acc[mt][nt2][i] * scale;
                if (BIAS == 1) v += bias[col];
                if (BIAS == 2) v += bias[row];
                if (ACT) v = fmaxf(v, 0.0f);
                if (RES) v += res[(long)bm * sRes + (long)row * ldC + col];
                const long ci = (long)bm * sC + (long)row * ldC + col;
                if (ATOM)        atomicAdd(&((float*)Cv)[ci], v);
                else if (OUTF32) ((float*)Cv)[ci] = v;
                else             ((u16*)Cv)[ci] = f2b(v);
            }
        }
    }
}

// ------- row softmax on scores(+v-term): 1024 f32 -> 1024 bf16 IN-PLACE (row stride 2048 u16) ----
__global__ __launch_bounds__(256) void k_softmax(float* __restrict__ sc, const float* __restrict__ vf,
                                                 float scl) {
    __shared__ float red[8];
    const int r = blockIdx.x;
    const int t = threadIdx.x;
    const int w = t >> 6;
    const int cb = (r >> 10) << 10;   // batch column base into vfull
    float* p = sc + (long)r * 1024;
    f32x4 v = reinterpret_cast<const f32x4*>(p)[t];
    f32x4 va = *reinterpret_cast<const f32x4*>(vf + cb + t * 4);
    v.x += va.x * scl; v.y += va.y * scl; v.z += va.z * scl; v.w += va.w * scl;
    float m = fmaxf(fmaxf(v.x, v.y), fmaxf(v.z, v.w));
    #pragma unroll
    for (int d = 32; d >= 1; d >>= 1) m = fmaxf(m, __shfl_xor(m, d));
    if ((t & 63) == 0) red[w] = m;
    __syncthreads();
    m = fmaxf(fmaxf(red[0], red[1]), fmaxf(red[2], red[3]));
    f32x4 e;
    e.x = __expf(v.x - m); e.y = __expf(v.y - m);
    e.z = __expf(v.z - m); e.w = __expf(v.w - m);
    float s = e.x + e.y + e.z + e.w;
    #pragma unroll
    for (int d = 32; d >= 1; d >>= 1) s += __shfl_xor(s, d);
    if ((t & 63) == 0) red[4 + w] = s;
    __syncthreads();
    s = red[4] + red[5] + red[6] + red[7];
    const float inv = 1.0f / s;
    ushort4 o;
    o.x = f2b(e.x * inv); o.y = f2b(e.y * inv);
    o.z = f2b(e.z * inv); o.w = f2b(e.w * inv);
    reinterpret_cast<ushort4*>(reinterpret_cast<u16*>(sc) + (long)r * 2048)[t] = o;
}

// ---------------- LayerNorm over D=512, one wave per row ----------------
__global__ __launch_bounds__(256) void k_layernorm(const float* __restrict__ in,
                                                   const float* __restrict__ g,
                                                   const float* __restrict__ be,
                                                   float* __restrict__ of,
                                                   u16* __restrict__ ob) {
    const int w = threadIdx.x >> 6;
    const int l = threadIdx.x & 63;
    const long row = (long)blockIdx.x * 4 + w;
    const float* p = in + row * 512;
    f32x4 v0 = *reinterpret_cast<const f32x4*>(p + l * 4);
    f32x4 v1 = *reinterpret_cast<const f32x4*>(p + 256 + l * 4);
    float s = v0.x + v0.y + v0.z + v0.w + v1.x + v1.y + v1.z + v1.w;
    float q = v0.x * v0.x + v0.y * v0.y + v0.z * v0.z + v0.w * v0.w
            + v1.x * v1.x + v1.y * v1.y + v1.z * v1.z + v1.w * v1.w;
    #pragma unroll
    for (int d = 32; d >= 1; d >>= 1) { s += __shfl_xor(s, d); q += __shfl_xor(q, d); }
    const float mean = s * (1.0f / 512.0f);
    const float var = q * (1.0f / 512.0f) - mean * mean;
    const float inv = rsqrtf(var + 1e-5f);
    f32x4 ga = *reinterpret_cast<const f32x4*>(g + l * 4);
    f32x4 gb = *reinterpret_cast<const f32x4*>(g + 256 + l * 4);
    f32x4 ba = *reinterpret_cast<const f32x4*>(be + l * 4);
    f32x4 bb = *reinterpret_cast<const f32x4*>(be + 256 + l * 4);
    f32x4 o0 = (v0 - mean) * inv * ga + ba;
    f32x4 o1 = (v1 - mean) * inv * gb + bb;
    *reinterpret_cast<f32x4*>(of + row * 512 + l * 4) = o0;
    *reinterpret_cast<f32x4*>(of + row * 512 + 256 + l * 4) = o1;
    if (ob) {
        ushort4 p0, p1;
        p0.x = f2b(o0.x); p0.y = f2b(o0.y); p0.z = f2b(o0.z); p0.w = f2b(o0.w);
        p1.x = f2b(o1.x); p1.y = f2b(o1.y); p1.z = f2b(o1.z); p1.w = f2b(o1.w);
        *reinterpret_cast<ushort4*>(ob + row * 512 + l * 4) = p0;
        *reinterpret_cast<ushort4*>(ob + row * 512 + 256 + l * 4) = p1;
    }
}

extern "C" void kernel_launch(void* const* d_in, const int* in_sizes, int n_in,
                              void* d_out, int out_size, void* d_ws, size_t ws_size,
                              hipStream_t stream) {
    const float* x   = (const float*)d_in[0];
    const float* Wq  = (const float*)d_in[1];
    const float* bq  = (const float*)d_in[2];
    const float* Wk  = (const float*)d_in[3];
    const float* bk  = (const float*)d_in[4];
    const float* Wv  = (const float*)d_in[5];
    const float* bv  = (const float*)d_in[6];
    const float* Wo  = (const float*)d_in[7];
    const float* bo  = (const float*)d_in[8];
    const float* g0  = (const float*)d_in[9];
    const float* be0 = (const float*)d_in[10];
    const float* W1  = (const float*)d_in[11];
    const float* b1  = (const float*)d_in[12];
    const float* W2  = (const float*)d_in[13];
    const float* b2  = (const float*)d_in[14];
    const float* g1  = (const float*)d_in[15];
    const float* be1 = (const float*)d_in[16];
    float* out = (float*)d_out;

    // ---- workspace layout (bytes), peak ~163.6 MB ----
    // Low-rank factorization: scores = X·M·X^T (+1·v^T), mha = (attn·X)·P^T + w0;
    // M = Wq^T·Wk, P = Wo·Wv are 512x512. Row-constant score terms dropped (softmax-invariant).
    char* ws = (char*)d_ws;
    u16*   xb    = (u16*)(ws + 0);             // [8192,512] bf16
    u16*   XTb   = (u16*)(ws + 8388608);       // [8][512,1024] bf16
    u16*   WkT   = (u16*)(ws + 25165824);      // [512,4096] bf16  (A-batch: WkT, Wob)
    u16*   Wob   = (u16*)(ws + 29360128);      // [512,4096] bf16
    u16*   WqT   = (u16*)(ws + 33554432);      // [512,4096] bf16  (B-batch: WqT, WvT)
    u16*   WvT   = (u16*)(ws + 37748736);      // [512,4096] bf16
    u16*   W1b   = (u16*)(ws + 41943040);
    u16*   W2b   = (u16*)(ws + 42467328);
    float* Mf32  = (float*)(ws + 42991616);    // [512,512] f32 (M^T), atomic dest
    float* Pf32  = (float*)(ws + 44040192);    // [512,512] f32
    u16*   MTb   = (u16*)(ws + 45088768);      // [512,512] bf16 (M^T)
    u16*   Pb    = (u16*)(ws + 45613056);      // [512,512] bf16
    float* v512  = (float*)(ws + 46137344);    // Wk^T·bq
    float* w0    = (float*)(ws + 46139392);    // Wo·bv + bo
    float* vfull = (float*)(ws + 46141440);    // X·v512 [8192]
    u16*   Yb    = (u16*)(ws + 46174208);      // [8192,512] bf16 = X·M
    u16*   Zb    = (u16*)(ws + 54562816);      // [8192,512] bf16 = attn·X
    float* hsum  = (float*)(ws + 62951424);    // [8192,512] f32
    float* hf    = (float*)(ws + 79728640);
    u16*   hb    = (u16*)(ws + 96505856);
    u16*   ff1b  = (u16*)(ws + 104894464);
    float* t2    = (float*)(ws + 113283072);
    float* scores= (float*)(ws + 130060288);   // [8,1024,1024] f32, attn bf16 in-place (ld 2048)
    u16*   attnb = (u16*)scores;

    hipMemsetAsync(Mf32, 0, 2097152, stream);  // zero M,P atomic accumulators

    // converts & transposes
    k_convert<<<4096, 256, 0, stream>>>(x, xb, 1048576);
    k_transpose<<<dim3(8, 64, 1), 256, 0, stream>>>(Wk, WkT, 4096, 512, 0, 0);
    k_transpose<<<dim3(8, 64, 1), 256, 0, stream>>>(Wq, WqT, 4096, 512, 0, 0);
    k_transpose<<<dim3(8, 64, 1), 256, 0, stream>>>(Wv, WvT, 4096, 512, 0, 0);
    k_convert<<<2048, 256, 0, stream>>>(Wo, Wob, 524288);
    k_convert<<<256,  256, 0, stream>>>(W1, W1b, 65536);
    k_convert<<<256,  256, 0, stream>>>(W2, W2b, 65536);
    k_transpose<<<dim3(8, 16, 8), 256, 0, stream>>>(x, XTb, 1024, 512, 524288, 524288);

    // exact bias terms
    k_colvec<<<512, 256, 0, stream>>>(Wk, bq, v512);           // v512 = Wk^T·bq
    k_rowvec<<<512, 256, 0, stream>>>(Wo, bv, bo, w0);         // w0 = Wo·bv + bo
    k_xv<<<2048, 256, 0, stream>>>(x, v512, vfull);            // vfull = X·v512

    const float scl = 0.044194173824159216f; // 1/sqrt(512)

    // [M^T | P] batched split-K(8): bm0: WkT·WqT^T = Wk^T·Wq = M^T; bm1: Wo·WvT^T = Wo·Wv = P
    gemm_nt<0,0,1,0,3,1><<<dim3(4,4,16), 256, 0, stream>>>(WkT,2097152, WqT,2097152, nullptr, nullptr,0, Mf32,262144, 4096,4096,512, 512, 1.0f);
    k_convert<<<512, 256, 0, stream>>>(Mf32, MTb, 131072);     // M^T,P f32 -> bf16 (adjacent)

    // Y = X·M  (NT with B = M^T)
    gemm_nt<0,0,0,0><<<dim3(4,64,1), 256, 0, stream>>>(xb,0, MTb,0, nullptr, nullptr,0, Yb,0, 512,512,512, 512, 1.0f);
    // scores[b] = scl·Y[b]·X[b]^T   f32 [8][1024,1024]
    gemm_nt<0,0,1,0><<<dim3(8,8,8), 256, 0, stream>>>(Yb,524288, xb,524288, nullptr, nullptr,0, scores,1048576, 512,512,1024, 512, scl);
    // attn = softmax(scores + scl·1·vfull^T) -> bf16 in-place
    k_softmax<<<8192, 256, 0, stream>>>(scores, vfull, scl);
    // Z[b] = attn[b]·X[b]  (NT with B = X[b]^T)
    gemm_nt<0,0,0,0><<<dim3(4,8,8), 256, 0, stream>>>(attnb,2097152, XTb,524288, nullptr, nullptr,0, Zb,524288, 2048,1024,512, 1024, 1.0f);
    // hsum = Z·P^T + w0 + x   f32 [8192,512]
    gemm_nt<1,0,1,1><<<dim3(4,64,1), 256, 0, stream>>>(Zb,0, Pb,0, w0, x,0, hsum,0, 512,512,512, 512, 1.0f);
    // h = LN(hsum)
    k_layernorm<<<2048, 256, 0, stream>>>(hsum, g0, be0, hf, hb);
    // ff1 = relu(h·W1^T + b1)
    gemm_nt<1,1,0,0><<<dim3(4,64,1), 256, 0, stream>>>(hb,0, W1b,0, b1, nullptr,0, ff1b,0, 512,512,512, 512, 1.0f);
    // t2 = ff1·W2^T + b2 + h
    gemm_nt<1,0,1,1><<<dim3(4,64,1), 256, 0, stream>>>(ff1b,0, W2b,0, b2, hf,0, t2,0, 512,512,512, 512, 1.0f);
    // out = LN(t2)
    k_layernorm<<<2048, 256, 0, stream>>>(t2, g1, be1, out, nullptr);
}